// Round 1
// baseline (1501.458 us; speedup 1.0000x reference)
//
#include <hip/hip_runtime.h>
#include <math.h>

#define LN_EPS 1e-5f

// ---------------- wave reduction helpers ----------------
__device__ __forceinline__ float wave_sum64(float v) {
#pragma unroll
  for (int m = 1; m <= 32; m <<= 1) v += __shfl_xor(v, m, 64);
  return v;
}
__device__ __forceinline__ float grp16_sum(float v) {
#pragma unroll
  for (int m = 1; m <= 8; m <<= 1) v += __shfl_xor(v, m, 64);
  return v;
}
__device__ __forceinline__ float grp16_max(float v) {
#pragma unroll
  for (int m = 1; m <= 8; m <<= 1) v = fmaxf(v, __shfl_xor(v, m, 64));
  return v;
}
__device__ __forceinline__ float grp32_sum(float v) {
#pragma unroll
  for (int m = 1; m <= 16; m <<= 1) v += __shfl_xor(v, m, 64);
  return v;
}

// ---------------- extractor + QKV projection (fused) ----------------
// One wave per row: LN(DM) -> Linear(DM,64) -> ReLU -> three 64x64 projections.
template <int DM>
__global__ __launch_bounds__(256) void extract_kernel(
    const float* __restrict__ xin, const float* __restrict__ lng,
    const float* __restrict__ lnb, const float* __restrict__ Wext,
    const float* __restrict__ bext, const float* __restrict__ Wq,
    const float* __restrict__ bq, const float* __restrict__ Wk,
    const float* __restrict__ bk, const float* __restrict__ Wv,
    const float* __restrict__ bv, float* __restrict__ featOut,
    float* __restrict__ Qout, float* __restrict__ Kout,
    float* __restrict__ Vout) {
  __shared__ float sWq[4096], sWk[4096], sWv[4096];
  __shared__ float ybuf[4][256];
  __shared__ float fbuf[4][64];
  const int t = threadIdx.x, w = t >> 6, lane = t & 63;
  for (int i = t; i < 4096; i += 256) {
    sWq[i] = Wq[i];
    sWk[i] = Wk[i];
    sWv[i] = Wv[i];
  }
  __syncthreads();
  for (int rr = 0; rr < 8; ++rr) {
    const int r = blockIdx.x * 32 + rr * 4 + w;
    const float* x = xin + (size_t)r * DM;
    float xr[4];
    float s = 0.f, ss = 0.f;
#pragma unroll
    for (int u = 0; u < 4; ++u) {
      const int idx = u * 64 + lane;
      const float v = (idx < DM) ? x[idx] : 0.f;
      xr[u] = v;
      s += v;
      ss += v * v;
    }
    s = wave_sum64(s);
    ss = wave_sum64(ss);
    const float mean = s / (float)DM;
    const float rstd = rsqrtf(ss / (float)DM - mean * mean + LN_EPS);
#pragma unroll
    for (int u = 0; u < 4; ++u) {
      const int idx = u * 64 + lane;
      if (idx < DM) ybuf[w][idx] = (xr[u] - mean) * rstd * lng[idx] + lnb[idx];
    }
    __syncthreads();
    float acc = bext[lane];
#pragma unroll 8
    for (int i = 0; i < DM; ++i) acc += ybuf[w][i] * Wext[i * 64 + lane];
    const float f = fmaxf(acc, 0.f);
    featOut[(size_t)r * 64 + lane] = f;
    fbuf[w][lane] = f;
    __syncthreads();
    float aq = bq[lane], ak = bk[lane], av = bv[lane];
#pragma unroll 8
    for (int i = 0; i < 64; ++i) {
      const float fv = fbuf[w][i];
      aq += fv * sWq[i * 64 + lane];
      ak += fv * sWk[i * 64 + lane];
      av += fv * sWv[i * 64 + lane];
    }
    Qout[(size_t)r * 64 + lane] = aq;
    Kout[(size_t)r * 64 + lane] = ak;
    Vout[(size_t)r * 64 + lane] = av;
  }
}

// ---------------- flash attention, f32 ----------------
// Grid 256: blocks 0..127 direction 0 (A1), 128..255 direction 1 (A2).
// 64-query x 64-key tiles, 256 threads, 4x4 register sub-tile per thread.
// LDS tiles stride-64 floats with XOR swizzle on bits 2..4 of the float index
// (keyed on row bits 2..4) -> hot reads conflict-free or 2-way.
__device__ __forceinline__ int sidx(int r, int c) {
  return ((r << 6) + c) ^ (((r >> 2) & 7) << 2);
}

__global__ __launch_bounds__(256) void attn_kernel(
    const float* __restrict__ Q0, const float* __restrict__ K0,
    const float* __restrict__ V0, float* __restrict__ O0,
    const float* __restrict__ Q1, const float* __restrict__ K1,
    const float* __restrict__ V1, float* __restrict__ O1) {
  __shared__ float Qs[4096], Ks[4096], Vs[4096], Ps[4096];
  int bid = blockIdx.x;
  const float *Q, *K, *V;
  float* O;
  if (bid < 128) {
    Q = Q0; K = K0; V = V0; O = O0;
  } else {
    Q = Q1; K = K1; V = V1; O = O1;
    bid -= 128;
  }
  const int t = threadIdx.x;
  const int tq = t >> 4, tk = t & 15;
  const int q0 = bid * 64;

  // stage Q tile, pre-scaled by 1/sqrt(64)
#pragma unroll
  for (int u = 0; u < 4; ++u) {
    const int fi = t + 256 * u;
    const int r = fi >> 4, c = (fi & 15) << 2;
    float4 v = *reinterpret_cast<const float4*>(Q + (q0 + r) * 64 + c);
    v.x *= 0.125f; v.y *= 0.125f; v.z *= 0.125f; v.w *= 0.125f;
    *reinterpret_cast<float4*>(&Qs[sidx(r, c)]) = v;
  }

  float4 acc[4];
  float m_run[4], l_run[4];
#pragma unroll
  for (int qi = 0; qi < 4; ++qi) {
    acc[qi] = make_float4(0.f, 0.f, 0.f, 0.f);
    m_run[qi] = -INFINITY;
    l_run[qi] = 0.f;
  }

  // register-staged K/V double buffer: prefetch tile 0
  float4 kreg[4], vreg[4];
#pragma unroll
  for (int u = 0; u < 4; ++u) {
    const int fi = t + 256 * u;
    const int r = fi >> 4, c = (fi & 15) << 2;
    kreg[u] = *reinterpret_cast<const float4*>(K + r * 64 + c);
    vreg[u] = *reinterpret_cast<const float4*>(V + r * 64 + c);
  }

  for (int kt = 0; kt < 128; ++kt) {
    __syncthreads();  // previous tile fully consumed
#pragma unroll
    for (int u = 0; u < 4; ++u) {
      const int fi = t + 256 * u;
      const int r = fi >> 4, c = (fi & 15) << 2;
      *reinterpret_cast<float4*>(&Ks[sidx(r, c)]) = kreg[u];
      *reinterpret_cast<float4*>(&Vs[sidx(r, c)]) = vreg[u];
    }
    if (kt + 1 < 128) {
      const int base = (kt + 1) * 64;
#pragma unroll
      for (int u = 0; u < 4; ++u) {
        const int fi = t + 256 * u;
        const int r = fi >> 4, c = (fi & 15) << 2;
        kreg[u] = *reinterpret_cast<const float4*>(K + (base + r) * 64 + c);
        vreg[u] = *reinterpret_cast<const float4*>(V + (base + r) * 64 + c);
      }
    }
    __syncthreads();  // staging visible; prefetch loads stay in flight

    // S = Q Ktile^T (already scaled)
    float s[4][4];
#pragma unroll
    for (int qi = 0; qi < 4; ++qi)
#pragma unroll
      for (int ki = 0; ki < 4; ++ki) s[qi][ki] = 0.f;
#pragma unroll
    for (int i = 0; i < 64; i += 4) {
      float4 qv[4], kv[4];
#pragma unroll
      for (int qi = 0; qi < 4; ++qi)
        qv[qi] = *reinterpret_cast<const float4*>(&Qs[sidx(tq * 4 + qi, i)]);
#pragma unroll
      for (int ki = 0; ki < 4; ++ki)
        kv[ki] = *reinterpret_cast<const float4*>(&Ks[sidx(tk * 4 + ki, i)]);
#pragma unroll
      for (int qi = 0; qi < 4; ++qi)
#pragma unroll
        for (int ki = 0; ki < 4; ++ki)
          s[qi][ki] += qv[qi].x * kv[ki].x + qv[qi].y * kv[ki].y +
                       qv[qi].z * kv[ki].z + qv[qi].w * kv[ki].w;
    }

    // online softmax (row groups = 16 lanes sharing tq)
#pragma unroll
    for (int qi = 0; qi < 4; ++qi) {
      float mloc = fmaxf(fmaxf(s[qi][0], s[qi][1]), fmaxf(s[qi][2], s[qi][3]));
      mloc = grp16_max(mloc);
      const float mnew = fmaxf(m_run[qi], mloc);
      const float alpha = __expf(m_run[qi] - mnew);
      float4 p;
      p.x = __expf(s[qi][0] - mnew);
      p.y = __expf(s[qi][1] - mnew);
      p.z = __expf(s[qi][2] - mnew);
      p.w = __expf(s[qi][3] - mnew);
      const float lloc = grp16_sum(p.x + p.y + p.z + p.w);
      l_run[qi] = l_run[qi] * alpha + lloc;
      m_run[qi] = mnew;
      acc[qi].x *= alpha; acc[qi].y *= alpha;
      acc[qi].z *= alpha; acc[qi].w *= alpha;
      *reinterpret_cast<float4*>(&Ps[sidx(tq * 4 + qi, tk * 4)]) = p;
    }
    __syncthreads();  // order Ps writes vs PV reads (cheap, safe)

    // O += P Vtile
#pragma unroll
    for (int k = 0; k < 64; k += 4) {
      float4 pv[4], vv[4];
#pragma unroll
      for (int qi = 0; qi < 4; ++qi)
        pv[qi] = *reinterpret_cast<const float4*>(&Ps[sidx(tq * 4 + qi, k)]);
#pragma unroll
      for (int kj = 0; kj < 4; ++kj)
        vv[kj] = *reinterpret_cast<const float4*>(&Vs[sidx(k + kj, tk * 4)]);
#pragma unroll
      for (int qi = 0; qi < 4; ++qi) {
        acc[qi].x += pv[qi].x * vv[0].x + pv[qi].y * vv[1].x +
                     pv[qi].z * vv[2].x + pv[qi].w * vv[3].x;
        acc[qi].y += pv[qi].x * vv[0].y + pv[qi].y * vv[1].y +
                     pv[qi].z * vv[2].y + pv[qi].w * vv[3].y;
        acc[qi].z += pv[qi].x * vv[0].z + pv[qi].y * vv[1].z +
                     pv[qi].z * vv[2].z + pv[qi].w * vv[3].z;
        acc[qi].w += pv[qi].x * vv[0].w + pv[qi].y * vv[1].w +
                     pv[qi].z * vv[2].w + pv[qi].w * vv[3].w;
      }
    }
  }

#pragma unroll
  for (int qi = 0; qi < 4; ++qi) {
    const float inv = 1.f / l_run[qi];
    float4 o = acc[qi];
    o.x *= inv; o.y *= inv; o.z *= inv; o.w *= inv;
    *reinterpret_cast<float4*>(O + (q0 + tq * 4 + qi) * 64 + tk * 4) = o;
  }
}

// ---------------- post: residual blocks + gate + head ----------------
__global__ __launch_bounds__(256) void post_kernel(
    const float* __restrict__ A1, const float* __restrict__ A2,
    const float* __restrict__ nirF, const float* __restrict__ libsF,
    const float* __restrict__ ln1g, const float* __restrict__ ln1b,
    const float* __restrict__ fc1w, const float* __restrict__ fc1b,
    const float* __restrict__ ln2g, const float* __restrict__ ln2b,
    const float* __restrict__ fc2w, const float* __restrict__ fc2b,
    const float* __restrict__ ln0g, const float* __restrict__ ln0b,
    const float* __restrict__ gatew, const float* __restrict__ gateb,
    const float* __restrict__ ln3g, const float* __restrict__ ln3b,
    const float* __restrict__ fc3w, const float* __restrict__ fc3b,
    const float* __restrict__ ln4g, const float* __restrict__ ln4b,
    const float* __restrict__ fc4w, const float* __restrict__ fc4b,
    float* __restrict__ out) {
  __shared__ float FC1[4096], FC2[4096], FC3[2048];
  __shared__ float rbuf[4][128];
  const int t = threadIdx.x, w = t >> 6, lane = t & 63;
  for (int i = t; i < 4096; i += 256) {
    FC1[i] = fc1w[i];
    FC2[i] = fc2w[i];
  }
  for (int i = t; i < 2048; i += 256) FC3[i] = fc3w[i];
  __syncthreads();
  for (int rr = 0; rr < 8; ++rr) {
    const int r = blockIdx.x * 32 + rr * 4 + w;
    const size_t ro = (size_t)r * 64;
    const float a1 = A1[ro + lane], a2 = A2[ro + lane];
    const float nv = nirF[ro + lane], lv = libsF[ro + lane];

    // out1 = relu(LN(A2; ln1) @ fc1 + b) + libs
    float s = wave_sum64(a2), ss = wave_sum64(a2 * a2);
    float mean = s * (1.f / 64);
    float rstd = rsqrtf(ss * (1.f / 64) - mean * mean + LN_EPS);
    rbuf[w][lane] = (a2 - mean) * rstd * ln1g[lane] + ln1b[lane];
    __syncthreads();
    float o1 = fc1b[lane];
#pragma unroll 8
    for (int i = 0; i < 64; ++i) o1 += rbuf[w][i] * FC1[i * 64 + lane];
    const float out1 = fmaxf(o1, 0.f) + lv;
    __syncthreads();

    // out2 = relu(LN(A1; ln2) @ fc2 + b) + nir
    s = wave_sum64(a1);
    ss = wave_sum64(a1 * a1);
    mean = s * (1.f / 64);
    rstd = rsqrtf(ss * (1.f / 64) - mean * mean + LN_EPS);
    rbuf[w][lane] = (a1 - mean) * rstd * ln2g[lane] + ln2b[lane];
    __syncthreads();
    float o2 = fc2b[lane];
#pragma unroll 8
    for (int i = 0; i < 64; ++i) o2 += rbuf[w][i] * FC2[i * 64 + lane];
    const float out2 = fmaxf(o2, 0.f) + nv;
    __syncthreads();

    // combined = LN(concat(out1,out2); ln0); gate = sigmoid(combined @ gatew + b)
    s = wave_sum64(out1 + out2);
    ss = wave_sum64(out1 * out1 + out2 * out2);
    mean = s * (1.f / 128);
    rstd = rsqrtf(ss * (1.f / 128) - mean * mean + LN_EPS);
    rbuf[w][lane] = (out1 - mean) * rstd * ln0g[lane] + ln0b[lane];
    rbuf[w][64 + lane] = (out2 - mean) * rstd * ln0g[64 + lane] + ln0b[64 + lane];
    __syncthreads();
    float g = gateb[lane];
#pragma unroll 8
    for (int i = 0; i < 128; ++i) g += rbuf[w][i] * gatew[i * 64 + lane];
    g = 1.f / (1.f + __expf(-g));
    const float fused = g * out1 + (1.f - g) * out2;
    __syncthreads();

    // head: LN -> fc3 -> relu -> LN -> fc4
    s = wave_sum64(fused);
    ss = wave_sum64(fused * fused);
    mean = s * (1.f / 64);
    rstd = rsqrtf(ss * (1.f / 64) - mean * mean + LN_EPS);
    rbuf[w][lane] = (fused - mean) * rstd * ln3g[lane] + ln3b[lane];
    __syncthreads();
    if (lane < 32) {
      float h = fc3b[lane];
#pragma unroll 8
      for (int i = 0; i < 64; ++i) h += rbuf[w][i] * FC3[i * 32 + lane];
      h = fmaxf(h, 0.f);
      const float hs = grp32_sum(h), hss = grp32_sum(h * h);
      const float hm = hs * (1.f / 32);
      const float hr = rsqrtf(hss * (1.f / 32) - hm * hm + LN_EPS);
      const float y4 = (h - hm) * hr * ln4g[lane] + ln4b[lane];
      const float part = grp32_sum(y4 * fc4w[lane]);
      if (lane == 0) out[r] = part + fc4b[0];
    }
  }
}

extern "C" void kernel_launch(void* const* d_in, const int* in_sizes, int n_in,
                              void* d_out, int out_size, void* d_ws,
                              size_t ws_size, hipStream_t stream) {
  const float* nir_data = (const float*)d_in[0];
  const float* libs_data = (const float*)d_in[1];
  const float* nir_ln_g = (const float*)d_in[2];
  const float* nir_ln_b = (const float*)d_in[3];
  const float* nir_w = (const float*)d_in[4];
  const float* nir_b = (const float*)d_in[5];
  const float* libs_ln_g = (const float*)d_in[6];
  const float* libs_ln_b = (const float*)d_in[7];
  const float* libs_w = (const float*)d_in[8];
  const float* libs_b = (const float*)d_in[9];
  const float* q_ln_w = (const float*)d_in[10];
  const float* q_ln_b = (const float*)d_in[11];
  const float* k_ln_w = (const float*)d_in[12];
  const float* k_ln_b = (const float*)d_in[13];
  const float* v_ln_w = (const float*)d_in[14];
  const float* v_ln_b = (const float*)d_in[15];
  const float* q_nl_w = (const float*)d_in[16];
  const float* q_nl_b = (const float*)d_in[17];
  const float* k_nl_w = (const float*)d_in[18];
  const float* k_nl_b = (const float*)d_in[19];
  const float* v_nl_w = (const float*)d_in[20];
  const float* v_nl_b = (const float*)d_in[21];
  const float* ln1_g = (const float*)d_in[22];
  const float* ln1_b = (const float*)d_in[23];
  const float* fc1_w = (const float*)d_in[24];
  const float* fc1_b = (const float*)d_in[25];
  const float* ln2_g = (const float*)d_in[26];
  const float* ln2_b = (const float*)d_in[27];
  const float* fc2_w = (const float*)d_in[28];
  const float* fc2_b = (const float*)d_in[29];
  const float* ln0_g = (const float*)d_in[30];
  const float* ln0_b = (const float*)d_in[31];
  const float* gate_w = (const float*)d_in[32];
  const float* gate_b = (const float*)d_in[33];
  const float* ln3_g = (const float*)d_in[34];
  const float* ln3_b = (const float*)d_in[35];
  const float* fc3_w = (const float*)d_in[36];
  const float* fc3_b = (const float*)d_in[37];
  const float* ln4_g = (const float*)d_in[38];
  const float* ln4_b = (const float*)d_in[39];
  const float* fc4_w = (const float*)d_in[40];
  const float* fc4_b = (const float*)d_in[41];

  float* ws = (float*)d_ws;
  const size_t S = (size_t)8192 * 64;
  float* f_nir = ws + 0 * S;
  float* f_libs = ws + 1 * S;
  float* Q_libs = ws + 2 * S;
  float* K_nir = ws + 3 * S;
  float* V_nir = ws + 4 * S;
  float* Q_nir = ws + 5 * S;
  float* K_libs = ws + 6 * S;
  float* V_libs = ws + 7 * S;
  float* A1 = ws + 8 * S;  // attn_libs_to_nir
  float* A2 = ws + 9 * S;  // attn_nir_to_libs

  // nir: K/V use *_ln weights, Q uses q_nl
  extract_kernel<215><<<256, 256, 0, stream>>>(
      nir_data, nir_ln_g, nir_ln_b, nir_w, nir_b, q_nl_w, q_nl_b, k_ln_w,
      k_ln_b, v_ln_w, v_ln_b, f_nir, Q_nir, K_nir, V_nir);
  // libs: Q uses q_ln, K/V use *_nl weights
  extract_kernel<244><<<256, 256, 0, stream>>>(
      libs_data, libs_ln_g, libs_ln_b, libs_w, libs_b, q_ln_w, q_ln_b, k_nl_w,
      k_nl_b, v_nl_w, v_nl_b, f_libs, Q_libs, K_libs, V_libs);

  attn_kernel<<<256, 256, 0, stream>>>(Q_libs, K_nir, V_nir, A1, Q_nir, K_libs,
                                       V_libs, A2);

  post_kernel<<<256, 256, 0, stream>>>(
      A1, A2, f_nir, f_libs, ln1_g, ln1_b, fc1_w, fc1_b, ln2_g, ln2_b, fc2_w,
      fc2_b, ln0_g, ln0_b, gate_w, gate_b, ln3_g, ln3_b, fc3_w, fc3_b, ln4_g,
      ln4_b, fc4_w, fc4_b, (float*)d_out);
}

// Round 2
// 365.686 us; speedup vs baseline: 4.1059x; 4.1059x over previous
//
#include <hip/hip_runtime.h>
#include <hip/hip_bf16.h>
#include <math.h>

#define LN_EPS 1e-5f

typedef __attribute__((ext_vector_type(8))) short short8;
typedef __attribute__((ext_vector_type(4))) float f32x4;

__device__ __forceinline__ unsigned short f2bf(float f) {
  __hip_bfloat16 h = __float2bfloat16(f);
  return __builtin_bit_cast(unsigned short, h);
}

// ---------------- wave reduction helpers ----------------
__device__ __forceinline__ float wave_sum64(float v) {
#pragma unroll
  for (int m = 1; m <= 32; m <<= 1) v += __shfl_xor(v, m, 64);
  return v;
}
__device__ __forceinline__ float grp16_sum(float v) {
#pragma unroll
  for (int m = 1; m <= 8; m <<= 1) v += __shfl_xor(v, m, 64);
  return v;
}
__device__ __forceinline__ float grp16_max(float v) {
#pragma unroll
  for (int m = 1; m <= 8; m <<= 1) v = fmaxf(v, __shfl_xor(v, m, 64));
  return v;
}
__device__ __forceinline__ float grp32_sum(float v) {
#pragma unroll
  for (int m = 1; m <= 16; m <<= 1) v += __shfl_xor(v, m, 64);
  return v;
}

// ---------------- extractor + QKV projection (fused) ----------------
template <int DM>
__global__ __launch_bounds__(256) void extract_kernel(
    const float* __restrict__ xin, const float* __restrict__ lng,
    const float* __restrict__ lnb, const float* __restrict__ Wext,
    const float* __restrict__ bext, const float* __restrict__ Wq,
    const float* __restrict__ bq, const float* __restrict__ Wk,
    const float* __restrict__ bk, const float* __restrict__ Wv,
    const float* __restrict__ bv, float* __restrict__ featOut,
    float* __restrict__ Qout, float* __restrict__ Kout,
    float* __restrict__ Vout) {
  __shared__ float sWq[4096], sWk[4096], sWv[4096];
  __shared__ float ybuf[4][256];
  __shared__ float fbuf[4][64];
  const int t = threadIdx.x, w = t >> 6, lane = t & 63;
  for (int i = t; i < 4096; i += 256) {
    sWq[i] = Wq[i];
    sWk[i] = Wk[i];
    sWv[i] = Wv[i];
  }
  __syncthreads();
  for (int rr = 0; rr < 4; ++rr) {
    const int r = blockIdx.x * 16 + rr * 4 + w;
    const float* x = xin + (size_t)r * DM;
    float xr[4];
    float s = 0.f, ss = 0.f;
#pragma unroll
    for (int u = 0; u < 4; ++u) {
      const int idx = u * 64 + lane;
      const float v = (idx < DM) ? x[idx] : 0.f;
      xr[u] = v;
      s += v;
      ss += v * v;
    }
    s = wave_sum64(s);
    ss = wave_sum64(ss);
    const float mean = s / (float)DM;
    const float rstd = rsqrtf(ss / (float)DM - mean * mean + LN_EPS);
#pragma unroll
    for (int u = 0; u < 4; ++u) {
      const int idx = u * 64 + lane;
      if (idx < DM) ybuf[w][idx] = (xr[u] - mean) * rstd * lng[idx] + lnb[idx];
    }
    __syncthreads();
    float acc = bext[lane];
#pragma unroll 8
    for (int i = 0; i < DM; ++i) acc += ybuf[w][i] * Wext[i * 64 + lane];
    const float f = fmaxf(acc, 0.f);
    featOut[(size_t)r * 64 + lane] = f;
    fbuf[w][lane] = f;
    __syncthreads();
    float aq = bq[lane], ak = bk[lane], av = bv[lane];
#pragma unroll 8
    for (int i = 0; i < 64; ++i) {
      const float fv = fbuf[w][i];
      aq += fv * sWq[i * 64 + lane];
      ak += fv * sWk[i * 64 + lane];
      av += fv * sWv[i * 64 + lane];
    }
    Qout[(size_t)r * 64 + lane] = aq;
    Kout[(size_t)r * 64 + lane] = ak;
    Vout[(size_t)r * 64 + lane] = av;
    __syncthreads();
  }
}

// ---------------- flash attention, bf16 MFMA ----------------
// Grid 256: blocks 0..127 dir0, 128..255 dir1. Block = 4 waves, 64 queries
// (16 q per wave). KV tile 64, 128 tiles. K LDS [64kv][64d] bf16, V LDS
// transposed [64d][64kv] bf16, both XOR-swizzled (idx ^= (row&7)<<3, ushort
// units) so all ds_read_b128 fragment reads are conflict-free. Per-wave P
// buffer [16q][64k] bf16, same swizzle. Reg-staged double buffer with one
// raw barrier per tile (lgkmcnt(0) only -> global prefetch spans barriers).
__global__ __launch_bounds__(256) void attn_mfma_kernel(
    const float* __restrict__ Q0, const float* __restrict__ K0,
    const float* __restrict__ V0, float* __restrict__ O0,
    const float* __restrict__ Q1, const float* __restrict__ K1,
    const float* __restrict__ V1, float* __restrict__ O1) {
  __shared__ __align__(16) unsigned short lds_k[2][4096];
  __shared__ __align__(16) unsigned short lds_vt[2][4096];
  __shared__ __align__(16) unsigned short lds_p[4][1024];

  int bid = blockIdx.x;
  const float *Q, *K, *V;
  float* O;
  if (bid < 128) {
    Q = Q0; K = K0; V = V0; O = O0;
  } else {
    Q = Q1; K = K1; V = V1; O = O1;
    bid -= 128;
  }

  const int t = threadIdx.x;
  const int w = t >> 6;
  const int lane = t & 63;
  const int g = lane >> 4;   // lane group 0..3
  const int l16 = lane & 15;
  const int qw = bid * 64 + w * 16;  // wave's query base

  // ---- Q fragments in registers, pre-scaled by 1/sqrt(64) ----
  short8 qa[2];
#pragma unroll
  for (int c = 0; c < 2; ++c) {
    const float* qp = Q + (size_t)(qw + l16) * 64 + 32 * c + 8 * g;
    const float4 v0 = *reinterpret_cast<const float4*>(qp);
    const float4 v1 = *reinterpret_cast<const float4*>(qp + 4);
    qa[c][0] = (short)f2bf(v0.x * 0.125f);
    qa[c][1] = (short)f2bf(v0.y * 0.125f);
    qa[c][2] = (short)f2bf(v0.z * 0.125f);
    qa[c][3] = (short)f2bf(v0.w * 0.125f);
    qa[c][4] = (short)f2bf(v1.x * 0.125f);
    qa[c][5] = (short)f2bf(v1.y * 0.125f);
    qa[c][6] = (short)f2bf(v1.z * 0.125f);
    qa[c][7] = (short)f2bf(v1.w * 0.125f);
  }

  f32x4 oacc[4];
  float m_run[4], l_run[4];
#pragma unroll
  for (int i = 0; i < 4; ++i) {
    oacc[i] = f32x4{0.f, 0.f, 0.f, 0.f};
    m_run[i] = -INFINITY;
    l_run[i] = 0.f;
  }

  // ---- staging: each thread owns 4 (kv,d0) cells of the 64x64 tile ----
  const int skv = t >> 4;          // 0..15
  const int sd0 = (t & 15) << 2;   // 0..60
  float4 kf[4], vf[4];

#define LOADT(tile_)                                                        \
  {                                                                         \
    _Pragma("unroll") for (int p = 0; p < 4; ++p) {                         \
      const int kv = p * 16 + skv;                                          \
      const size_t off = ((size_t)((tile_)*64 + kv)) * 64 + sd0;            \
      kf[p] = *reinterpret_cast<const float4*>(K + off);                    \
      vf[p] = *reinterpret_cast<const float4*>(V + off);                    \
    }                                                                       \
  }

#define STORET(b_)                                                          \
  {                                                                         \
    _Pragma("unroll") for (int p = 0; p < 4; ++p) {                         \
      const int kv = p * 16 + skv;                                          \
      ushort4 kk;                                                           \
      kk.x = f2bf(kf[p].x);                                                 \
      kk.y = f2bf(kf[p].y);                                                 \
      kk.z = f2bf(kf[p].z);                                                 \
      kk.w = f2bf(kf[p].w);                                                 \
      *reinterpret_cast<ushort4*>(                                          \
          &lds_k[b_][(kv * 64 + sd0) ^ ((kv & 7) << 3)]) = kk;              \
      lds_vt[b_][((sd0 + 0) * 64 + kv) ^ (((sd0 + 0) & 7) << 3)] =          \
          f2bf(vf[p].x);                                                    \
      lds_vt[b_][((sd0 + 1) * 64 + kv) ^ (((sd0 + 1) & 7) << 3)] =          \
          f2bf(vf[p].y);                                                    \
      lds_vt[b_][((sd0 + 2) * 64 + kv) ^ (((sd0 + 2) & 7) << 3)] =          \
          f2bf(vf[p].z);                                                    \
      lds_vt[b_][((sd0 + 3) * 64 + kv) ^ (((sd0 + 3) & 7) << 3)] =          \
          f2bf(vf[p].w);                                                    \
    }                                                                       \
  }

  LOADT(0);
  STORET(0);  // compiler inserts vmcnt waits for kf/vf
  LOADT(1);
  asm volatile("s_waitcnt lgkmcnt(0)" ::: "memory");
  __builtin_amdgcn_s_barrier();
  asm volatile("" ::: "memory");

  for (int tile = 0; tile < 128; ++tile) {
    const int cur = tile & 1;

    // ---- S = Q K^T ----
    f32x4 sacc[4];
#pragma unroll
    for (int kb = 0; kb < 4; ++kb) sacc[kb] = f32x4{0.f, 0.f, 0.f, 0.f};
#pragma unroll
    for (int c = 0; c < 2; ++c) {
#pragma unroll
      for (int kb = 0; kb < 4; ++kb) {
        const int row = 16 * kb + l16;
        const int idx = (row * 64 + 32 * c + 8 * g) ^ ((row & 7) << 3);
        const short8 kfrag = *reinterpret_cast<const short8*>(&lds_k[cur][idx]);
        sacc[kb] =
            __builtin_amdgcn_mfma_f32_16x16x32_bf16(qa[c], kfrag, sacc[kb], 0, 0, 0);
      }
    }

    // ---- online softmax (row q = qw + 4g + r, cols spread over 16 lanes) ----
    float pm[4];
#pragma unroll
    for (int r = 0; r < 4; ++r) {
      float mx = fmaxf(fmaxf(sacc[0][r], sacc[1][r]),
                       fmaxf(sacc[2][r], sacc[3][r]));
      pm[r] = grp16_max(mx);
    }
    const bool grown = (pm[0] > m_run[0] + 4.f) || (pm[1] > m_run[1] + 4.f) ||
                       (pm[2] > m_run[2] + 4.f) || (pm[3] > m_run[3] + 4.f);
    if (__any(grown)) {
#pragma unroll
      for (int r = 0; r < 4; ++r) {
        const float mn = fmaxf(m_run[r], pm[r]);
        const float alpha = __expf(m_run[r] - mn);
        m_run[r] = mn;
        l_run[r] *= alpha;
#pragma unroll
        for (int db = 0; db < 4; ++db) oacc[db][r] *= alpha;
      }
    }
#pragma unroll
    for (int r = 0; r < 4; ++r) {
      const int prow = 4 * g + r;
      float rs = 0.f;
#pragma unroll
      for (int kb = 0; kb < 4; ++kb) {
        const float p = __expf(sacc[kb][r] - m_run[r]);
        rs += p;
        lds_p[w][(prow * 64 + 16 * kb + l16) ^ ((prow & 7) << 3)] = f2bf(p);
      }
      l_run[r] += grp16_sum(rs);
    }

    // ---- O += P V (per-wave P buffer; in-wave DS order guarantees wr->rd) ----
    short8 pa[2];
#pragma unroll
    for (int c = 0; c < 2; ++c) {
      const int idx = (l16 * 64 + 32 * c + 8 * g) ^ ((l16 & 7) << 3);
      pa[c] = *reinterpret_cast<const short8*>(&lds_p[w][idx]);
    }
#pragma unroll
    for (int c = 0; c < 2; ++c) {
#pragma unroll
      for (int db = 0; db < 4; ++db) {
        const int row = 16 * db + l16;
        const int idx = (row * 64 + 32 * c + 8 * g) ^ ((row & 7) << 3);
        const short8 vfrag =
            *reinterpret_cast<const short8*>(&lds_vt[cur][idx]);
        oacc[db] =
            __builtin_amdgcn_mfma_f32_16x16x32_bf16(pa[c], vfrag, oacc[db], 0, 0, 0);
      }
    }

    // ---- stage tile+1 into the other buffer, prefetch tile+2 ----
    if (tile < 127) {
      STORET(cur ^ 1);
      if (tile < 126) LOADT(tile + 2);
    }
    asm volatile("s_waitcnt lgkmcnt(0)" ::: "memory");
    __builtin_amdgcn_s_barrier();
    asm volatile("" ::: "memory");
  }

  // ---- epilogue: divide by l, store f32 ----
#pragma unroll
  for (int r = 0; r < 4; ++r) {
    const float inv = 1.f / l_run[r];
    const size_t rowoff = (size_t)(qw + 4 * g + r) * 64;
#pragma unroll
    for (int db = 0; db < 4; ++db)
      O[rowoff + 16 * db + l16] = oacc[db][r] * inv;
  }
#undef LOADT
#undef STORET
}

// ---------------- post: residual blocks + gate + head ----------------
__global__ __launch_bounds__(256) void post_kernel(
    const float* __restrict__ A1, const float* __restrict__ A2,
    const float* __restrict__ nirF, const float* __restrict__ libsF,
    const float* __restrict__ ln1g, const float* __restrict__ ln1b,
    const float* __restrict__ fc1w, const float* __restrict__ fc1b,
    const float* __restrict__ ln2g, const float* __restrict__ ln2b,
    const float* __restrict__ fc2w, const float* __restrict__ fc2b,
    const float* __restrict__ ln0g, const float* __restrict__ ln0b,
    const float* __restrict__ gatew, const float* __restrict__ gateb,
    const float* __restrict__ ln3g, const float* __restrict__ ln3b,
    const float* __restrict__ fc3w, const float* __restrict__ fc3b,
    const float* __restrict__ ln4g, const float* __restrict__ ln4b,
    const float* __restrict__ fc4w, const float* __restrict__ fc4b,
    float* __restrict__ out) {
  __shared__ float FC1[4096], FC2[4096], FC3[2048];
  __shared__ float rbuf[4][128];
  const int t = threadIdx.x, w = t >> 6, lane = t & 63;
  for (int i = t; i < 4096; i += 256) {
    FC1[i] = fc1w[i];
    FC2[i] = fc2w[i];
  }
  for (int i = t; i < 2048; i += 256) FC3[i] = fc3w[i];
  __syncthreads();
  for (int rr = 0; rr < 4; ++rr) {
    const int r = blockIdx.x * 16 + rr * 4 + w;
    const size_t ro = (size_t)r * 64;
    const float a1 = A1[ro + lane], a2 = A2[ro + lane];
    const float nv = nirF[ro + lane], lv = libsF[ro + lane];

    float s = wave_sum64(a2), ss = wave_sum64(a2 * a2);
    float mean = s * (1.f / 64);
    float rstd = rsqrtf(ss * (1.f / 64) - mean * mean + LN_EPS);
    rbuf[w][lane] = (a2 - mean) * rstd * ln1g[lane] + ln1b[lane];
    __syncthreads();
    float o1 = fc1b[lane];
#pragma unroll 8
    for (int i = 0; i < 64; ++i) o1 += rbuf[w][i] * FC1[i * 64 + lane];
    const float out1 = fmaxf(o1, 0.f) + lv;
    __syncthreads();

    s = wave_sum64(a1);
    ss = wave_sum64(a1 * a1);
    mean = s * (1.f / 64);
    rstd = rsqrtf(ss * (1.f / 64) - mean * mean + LN_EPS);
    rbuf[w][lane] = (a1 - mean) * rstd * ln2g[lane] + ln2b[lane];
    __syncthreads();
    float o2 = fc2b[lane];
#pragma unroll 8
    for (int i = 0; i < 64; ++i) o2 += rbuf[w][i] * FC2[i * 64 + lane];
    const float out2 = fmaxf(o2, 0.f) + nv;
    __syncthreads();

    s = wave_sum64(out1 + out2);
    ss = wave_sum64(out1 * out1 + out2 * out2);
    mean = s * (1.f / 128);
    rstd = rsqrtf(ss * (1.f / 128) - mean * mean + LN_EPS);
    rbuf[w][lane] = (out1 - mean) * rstd * ln0g[lane] + ln0b[lane];
    rbuf[w][64 + lane] =
        (out2 - mean) * rstd * ln0g[64 + lane] + ln0b[64 + lane];
    __syncthreads();
    float gg = gateb[lane];
#pragma unroll 8
    for (int i = 0; i < 128; ++i) gg += rbuf[w][i] * gatew[i * 64 + lane];
    gg = 1.f / (1.f + __expf(-gg));
    const float fused = gg * out1 + (1.f - gg) * out2;
    __syncthreads();

    s = wave_sum64(fused);
    ss = wave_sum64(fused * fused);
    mean = s * (1.f / 64);
    rstd = rsqrtf(ss * (1.f / 64) - mean * mean + LN_EPS);
    rbuf[w][lane] = (fused - mean) * rstd * ln3g[lane] + ln3b[lane];
    __syncthreads();
    if (lane < 32) {
      float h = fc3b[lane];
#pragma unroll 8
      for (int i = 0; i < 64; ++i) h += rbuf[w][i] * FC3[i * 32 + lane];
      h = fmaxf(h, 0.f);
      const float hs = grp32_sum(h), hss = grp32_sum(h * h);
      const float hm = hs * (1.f / 32);
      const float hr = rsqrtf(hss * (1.f / 32) - hm * hm + LN_EPS);
      const float y4 = (h - hm) * hr * ln4g[lane] + ln4b[lane];
      const float part = grp32_sum(y4 * fc4w[lane]);
      if (lane == 0) out[r] = part + fc4b[0];
    }
    __syncthreads();
  }
}

extern "C" void kernel_launch(void* const* d_in, const int* in_sizes, int n_in,
                              void* d_out, int out_size, void* d_ws,
                              size_t ws_size, hipStream_t stream) {
  const float* nir_data = (const float*)d_in[0];
  const float* libs_data = (const float*)d_in[1];
  const float* nir_ln_g = (const float*)d_in[2];
  const float* nir_ln_b = (const float*)d_in[3];
  const float* nir_w = (const float*)d_in[4];
  const float* nir_b = (const float*)d_in[5];
  const float* libs_ln_g = (const float*)d_in[6];
  const float* libs_ln_b = (const float*)d_in[7];
  const float* libs_w = (const float*)d_in[8];
  const float* libs_b = (const float*)d_in[9];
  const float* q_ln_w = (const float*)d_in[10];
  const float* q_ln_b = (const float*)d_in[11];
  const float* k_ln_w = (const float*)d_in[12];
  const float* k_ln_b = (const float*)d_in[13];
  const float* v_ln_w = (const float*)d_in[14];
  const float* v_ln_b = (const float*)d_in[15];
  const float* q_nl_w = (const float*)d_in[16];
  const float* q_nl_b = (const float*)d_in[17];
  const float* k_nl_w = (const float*)d_in[18];
  const float* k_nl_b = (const float*)d_in[19];
  const float* v_nl_w = (const float*)d_in[20];
  const float* v_nl_b = (const float*)d_in[21];
  const float* ln1_g = (const float*)d_in[22];
  const float* ln1_b = (const float*)d_in[23];
  const float* fc1_w = (const float*)d_in[24];
  const float* fc1_b = (const float*)d_in[25];
  const float* ln2_g = (const float*)d_in[26];
  const float* ln2_b = (const float*)d_in[27];
  const float* fc2_w = (const float*)d_in[28];
  const float* fc2_b = (const float*)d_in[29];
  const float* ln0_g = (const float*)d_in[30];
  const float* ln0_b = (const float*)d_in[31];
  const float* gate_w = (const float*)d_in[32];
  const float* gate_b = (const float*)d_in[33];
  const float* ln3_g = (const float*)d_in[34];
  const float* ln3_b = (const float*)d_in[35];
  const float* fc3_w = (const float*)d_in[36];
  const float* fc3_b = (const float*)d_in[37];
  const float* ln4_g = (const float*)d_in[38];
  const float* ln4_b = (const float*)d_in[39];
  const float* fc4_w = (const float*)d_in[40];
  const float* fc4_b = (const float*)d_in[41];

  float* ws = (float*)d_ws;
  const size_t S = (size_t)8192 * 64;
  float* f_nir = ws + 0 * S;
  float* f_libs = ws + 1 * S;
  float* Q_libs = ws + 2 * S;
  float* K_nir = ws + 3 * S;
  float* V_nir = ws + 4 * S;
  float* Q_nir = ws + 5 * S;
  float* K_libs = ws + 6 * S;
  float* V_libs = ws + 7 * S;
  float* A1 = ws + 8 * S;  // attn_libs_to_nir
  float* A2 = ws + 9 * S;  // attn_nir_to_libs

  extract_kernel<215><<<512, 256, 0, stream>>>(
      nir_data, nir_ln_g, nir_ln_b, nir_w, nir_b, q_nl_w, q_nl_b, k_ln_w,
      k_ln_b, v_ln_w, v_ln_b, f_nir, Q_nir, K_nir, V_nir);
  extract_kernel<244><<<512, 256, 0, stream>>>(
      libs_data, libs_ln_g, libs_ln_b, libs_w, libs_b, q_ln_w, q_ln_b, k_nl_w,
      k_nl_b, v_nl_w, v_nl_b, f_libs, Q_libs, K_libs, V_libs);

  attn_mfma_kernel<<<256, 256, 0, stream>>>(Q_libs, K_nir, V_nir, A1, Q_nir,
                                            K_libs, V_libs, A2);

  post_kernel<<<512, 256, 0, stream>>>(
      A1, A2, f_nir, f_libs, ln1_g, ln1_b, fc1_w, fc1_b, ln2_g, ln2_b, fc2_w,
      fc2_b, ln0_g, ln0_b, gate_w, gate_b, ln3_g, ln3_b, fc3_w, fc3_b, ln4_g,
      ln4_b, fc4_w, fc4_b, (float*)d_out);
}

// Round 3
// 245.872 us; speedup vs baseline: 6.1067x; 1.4873x over previous
//
#include <hip/hip_runtime.h>
#include <hip/hip_bf16.h>
#include <math.h>

#define LN_EPS 1e-5f

typedef __attribute__((ext_vector_type(8))) short short8;
typedef __attribute__((ext_vector_type(4))) float f32x4;
typedef unsigned short u16;

__device__ __forceinline__ u16 f2bf(float f) {
  __hip_bfloat16 h = __float2bfloat16(f);
  return __builtin_bit_cast(u16, h);
}
__device__ __forceinline__ float bf2f(u16 u) {
  unsigned int x = ((unsigned int)u) << 16;
  return __builtin_bit_cast(float, x);
}

// ---------------- wave reduction helpers ----------------
__device__ __forceinline__ float wave_sum64(float v) {
#pragma unroll
  for (int m = 1; m <= 32; m <<= 1) v += __shfl_xor(v, m, 64);
  return v;
}
__device__ __forceinline__ float grp16_sum(float v) {
#pragma unroll
  for (int m = 1; m <= 8; m <<= 1) v += __shfl_xor(v, m, 64);
  return v;
}
__device__ __forceinline__ float grp16_max(float v) {
#pragma unroll
  for (int m = 1; m <= 8; m <<= 1) v = fmaxf(v, __shfl_xor(v, m, 64));
  return v;
}
__device__ __forceinline__ float grp32_sum(float v) {
#pragma unroll
  for (int m = 1; m <= 16; m <<= 1) v += __shfl_xor(v, m, 64);
  return v;
}

// ---------------- extractor + QKV projection (fused) ----------------
// Weights staged in LDS as bf16 (57KB -> 2 blocks/CU). Q output pre-scaled
// by 1/sqrt(64) and Q/K/V emitted as bf16 for the MFMA attention.
template <int DM>
__global__ __launch_bounds__(256) void extract_kernel(
    const float* __restrict__ xin, const float* __restrict__ lng,
    const float* __restrict__ lnb, const float* __restrict__ Wext,
    const float* __restrict__ bext, const float* __restrict__ Wq,
    const float* __restrict__ bq, const float* __restrict__ Wk,
    const float* __restrict__ bk, const float* __restrict__ Wv,
    const float* __restrict__ bv, float* __restrict__ featOut,
    u16* __restrict__ Qout, u16* __restrict__ Kout, u16* __restrict__ Vout) {
  __shared__ u16 sWe[DM * 64];
  __shared__ u16 sWq[4096], sWk[4096], sWv[4096];
  __shared__ float ybuf[4][256];
  __shared__ float fbuf[4][64];
  const int t = threadIdx.x, w = t >> 6, lane = t & 63;
  for (int i = t; i < DM * 64; i += 256) sWe[i] = f2bf(Wext[i]);
  for (int i = t; i < 4096; i += 256) {
    sWq[i] = f2bf(Wq[i]);
    sWk[i] = f2bf(Wk[i]);
    sWv[i] = f2bf(Wv[i]);
  }
  __syncthreads();
  for (int rr = 0; rr < 4; ++rr) {
    const int r = blockIdx.x * 16 + rr * 4 + w;
    const float* x = xin + (size_t)r * DM;
    float xr[4];
    float s = 0.f, ss = 0.f;
#pragma unroll
    for (int u = 0; u < 4; ++u) {
      const int idx = u * 64 + lane;
      const float v = (idx < DM) ? x[idx] : 0.f;
      xr[u] = v;
      s += v;
      ss += v * v;
    }
    s = wave_sum64(s);
    ss = wave_sum64(ss);
    const float mean = s / (float)DM;
    const float rstd = rsqrtf(ss / (float)DM - mean * mean + LN_EPS);
#pragma unroll
    for (int u = 0; u < 4; ++u) {
      const int idx = u * 64 + lane;
      if (idx < DM) ybuf[w][idx] = (xr[u] - mean) * rstd * lng[idx] + lnb[idx];
    }
    __syncthreads();
    float acc = bext[lane];
#pragma unroll 8
    for (int i = 0; i < DM; ++i) acc += ybuf[w][i] * bf2f(sWe[i * 64 + lane]);
    const float f = fmaxf(acc, 0.f);
    featOut[(size_t)r * 64 + lane] = f;
    fbuf[w][lane] = f;
    __syncthreads();
    float aq = bq[lane], ak = bk[lane], av = bv[lane];
#pragma unroll 8
    for (int i = 0; i < 64; ++i) {
      const float fv = fbuf[w][i];
      aq += fv * bf2f(sWq[i * 64 + lane]);
      ak += fv * bf2f(sWk[i * 64 + lane]);
      av += fv * bf2f(sWv[i * 64 + lane]);
    }
    Qout[(size_t)r * 64 + lane] = f2bf(aq * 0.125f);  // fold 1/sqrt(64)
    Kout[(size_t)r * 64 + lane] = f2bf(ak);
    Vout[(size_t)r * 64 + lane] = f2bf(av);
    __syncthreads();
  }
}

// ---------------- flash attention, bf16 MFMA, KV-split x4 ----------------
// grid 1024. bid&7 selects (dir,split) -> one (dir,split) per XCD so each
// XCD's L2 holds its 1MB KV slice. qt = bid>>3 (128 q-tiles of 64).
// Each block: 64 q, 2048 kv (32 tiles). Partial O (unnormalized) + m,l out.
// Swizzles (ushort idx, XOR bits>=3 only, 16B-alignment-safe):
//   K,P: ^ (row&7)<<3      V^T: ^ ((row>>1)&7)<<3
// All fragment reads spread evenly over bank-quads; writes <=2-way.
__global__ __launch_bounds__(256) void attn_mfma_kernel(
    const u16* __restrict__ Qb0, const u16* __restrict__ Kb0,
    const u16* __restrict__ Vb0, const u16* __restrict__ Qb1,
    const u16* __restrict__ Kb1, const u16* __restrict__ Vb1,
    float* __restrict__ Opart, float* __restrict__ mpart,
    float* __restrict__ lpart) {
  __shared__ __align__(16) u16 lds_k[2][4096];
  __shared__ __align__(16) u16 lds_vt[2][4096];
  __shared__ __align__(16) u16 lds_p[4][1024];

  const int bid = blockIdx.x;
  const int split = bid & 3;
  const int dir = (bid >> 2) & 1;
  const int qt = bid >> 3;
  const int slab = dir * 4 + split;
  const int kvbase = split * 2048;

  const u16* Q = dir ? Qb1 : Qb0;
  const u16* K = dir ? Kb1 : Kb0;
  const u16* V = dir ? Vb1 : Vb0;

  const int t = threadIdx.x;
  const int w = t >> 6;
  const int lane = t & 63;
  const int g = lane >> 4;
  const int l16 = lane & 15;
  const int q0 = qt * 64;
  const int qw = q0 + w * 16;

  // ---- Q fragments (already scaled by 1/8 at extract) ----
  short8 qa[2];
#pragma unroll
  for (int c = 0; c < 2; ++c)
    qa[c] = *reinterpret_cast<const short8*>(Q + (size_t)(qw + l16) * 64 +
                                             32 * c + 8 * g);

  f32x4 oacc[4];
  float m_run[4], l_run[4];
#pragma unroll
  for (int i = 0; i < 4; ++i) {
    oacc[i] = f32x4{0.f, 0.f, 0.f, 0.f};
    m_run[i] = -INFINITY;
    l_run[i] = 0.f;
  }

  // ---- staging: thread owns kv rows kv0..kv0+3, d cols d0..d0+3 ----
  const int kv0 = (t >> 4) << 2;
  const int d0 = (t & 15) << 2;
  ushort4 kh[4], vh[4];

#define LOADT(tile_)                                                         \
  {                                                                          \
    _Pragma("unroll") for (int j = 0; j < 4; ++j) {                          \
      const size_t off =                                                     \
          ((size_t)(kvbase + (tile_)*64 + kv0 + j)) * 64 + d0;               \
      kh[j] = *reinterpret_cast<const ushort4*>(K + off);                    \
      vh[j] = *reinterpret_cast<const ushort4*>(V + off);                    \
    }                                                                        \
  }

#define STORET(b_)                                                           \
  {                                                                          \
    _Pragma("unroll") for (int j = 0; j < 4; ++j) {                          \
      const int row = kv0 + j;                                               \
      *reinterpret_cast<ushort4*>(                                           \
          &lds_k[b_][(row * 64 + d0) ^ ((row & 7) << 3)]) = kh[j];           \
    }                                                                        \
    _Pragma("unroll") for (int i = 0; i < 4; ++i) {                          \
      const int row = d0 + i;                                                \
      ushort4 vt;                                                            \
      vt.x = (&vh[0].x)[i];                                                  \
      vt.y = (&vh[1].x)[i];                                                  \
      vt.z = (&vh[2].x)[i];                                                  \
      vt.w = (&vh[3].x)[i];                                                  \
      *reinterpret_cast<ushort4*>(                                           \
          &lds_vt[b_][(row * 64 + kv0) ^ (((row >> 1) & 7) << 3)]) = vt;     \
    }                                                                        \
  }

  LOADT(0);
  STORET(0);
  LOADT(1);
  asm volatile("s_waitcnt lgkmcnt(0)" ::: "memory");
  __builtin_amdgcn_s_barrier();
  asm volatile("" ::: "memory");

  for (int tile = 0; tile < 32; ++tile) {
    const int cur = tile & 1;

    // ---- S = Q K^T ----
    f32x4 sacc[4];
#pragma unroll
    for (int kb = 0; kb < 4; ++kb) sacc[kb] = f32x4{0.f, 0.f, 0.f, 0.f};
#pragma unroll
    for (int c = 0; c < 2; ++c) {
#pragma unroll
      for (int kb = 0; kb < 4; ++kb) {
        const int row = 16 * kb + l16;
        const int idx = (row * 64 + 32 * c + 8 * g) ^ ((row & 7) << 3);
        const short8 kfrag =
            *reinterpret_cast<const short8*>(&lds_k[cur][idx]);
        sacc[kb] = __builtin_amdgcn_mfma_f32_16x16x32_bf16(qa[c], kfrag,
                                                           sacc[kb], 0, 0, 0);
      }
    }

    // ---- online softmax, defer-max (THR=4) ----
    float pm[4];
#pragma unroll
    for (int r = 0; r < 4; ++r) {
      float mx = fmaxf(fmaxf(sacc[0][r], sacc[1][r]),
                       fmaxf(sacc[2][r], sacc[3][r]));
      pm[r] = grp16_max(mx);
    }
    const bool grown = (pm[0] > m_run[0] + 4.f) || (pm[1] > m_run[1] + 4.f) ||
                       (pm[2] > m_run[2] + 4.f) || (pm[3] > m_run[3] + 4.f);
    if (__any(grown)) {
#pragma unroll
      for (int r = 0; r < 4; ++r) {
        const float mn = fmaxf(m_run[r], pm[r]);
        const float alpha = __expf(m_run[r] - mn);
        m_run[r] = mn;
        l_run[r] *= alpha;
#pragma unroll
        for (int db = 0; db < 4; ++db) oacc[db][r] *= alpha;
      }
    }
#pragma unroll
    for (int r = 0; r < 4; ++r) {
      const int prow = 4 * g + r;
      float rs = 0.f;
#pragma unroll
      for (int kb = 0; kb < 4; ++kb) {
        const float p = __expf(sacc[kb][r] - m_run[r]);
        rs += p;
        lds_p[w][(prow * 64 + 16 * kb + l16) ^ ((prow & 7) << 3)] = f2bf(p);
      }
      l_run[r] += grp16_sum(rs);
    }

    // ---- O += P V (per-wave P; in-wave DS ordering by compiler) ----
    short8 pa[2];
#pragma unroll
    for (int c = 0; c < 2; ++c) {
      const int idx = (l16 * 64 + 32 * c + 8 * g) ^ ((l16 & 7) << 3);
      pa[c] = *reinterpret_cast<const short8*>(&lds_p[w][idx]);
    }
#pragma unroll
    for (int c = 0; c < 2; ++c) {
#pragma unroll
      for (int db = 0; db < 4; ++db) {
        const int row = 16 * db + l16;
        const int idx = (row * 64 + 32 * c + 8 * g) ^ (((row >> 1) & 7) << 3);
        const short8 vfrag =
            *reinterpret_cast<const short8*>(&lds_vt[cur][idx]);
        oacc[db] = __builtin_amdgcn_mfma_f32_16x16x32_bf16(pa[c], vfrag,
                                                           oacc[db], 0, 0, 0);
      }
    }

    // ---- stage tile+1, prefetch tile+2 ----
    if (tile < 31) {
      STORET(cur ^ 1);
      if (tile < 30) LOADT(tile + 2);
    }
    asm volatile("s_waitcnt lgkmcnt(0)" ::: "memory");
    __builtin_amdgcn_s_barrier();
    asm volatile("" ::: "memory");
  }

  // ---- store unnormalized partials + m,l ----
  const size_t S = (size_t)8192 * 64;
#pragma unroll
  for (int r = 0; r < 4; ++r) {
    const int row = qw + 4 * g + r;
#pragma unroll
    for (int db = 0; db < 4; ++db)
      Opart[(size_t)slab * S + (size_t)row * 64 + 16 * db + l16] =
          oacc[db][r];
  }
  if (l16 == 0) {
#pragma unroll
    for (int r = 0; r < 4; ++r) {
      const int row = qw + 4 * g + r;
      mpart[slab * 8192 + row] = m_run[r];
      lpart[slab * 8192 + row] = l_run[r];
    }
  }
#undef LOADT
#undef STORET
}

// ---------------- merge the 4 KV-splits ----------------
__global__ __launch_bounds__(256) void merge_kernel(
    const float* __restrict__ Opart, const float* __restrict__ mpart,
    const float* __restrict__ lpart, float* __restrict__ A1,
    float* __restrict__ A2) {
  const int t = threadIdx.x, w = t >> 6, lane = t & 63;
  const size_t S = (size_t)8192 * 64;
#pragma unroll
  for (int rr = 0; rr < 4; ++rr) {
    const int gr = blockIdx.x * 16 + w * 4 + rr;
    const int dir = gr >> 13;
    const int row = gr & 8191;
    float m[4], l[4];
#pragma unroll
    for (int s = 0; s < 4; ++s) {
      m[s] = mpart[(dir * 4 + s) * 8192 + row];
      l[s] = lpart[(dir * 4 + s) * 8192 + row];
    }
    const float mM = fmaxf(fmaxf(m[0], m[1]), fmaxf(m[2], m[3]));
    float wsum = 0.f, o = 0.f;
#pragma unroll
    for (int s = 0; s < 4; ++s) {
      const float wgt = __expf(m[s] - mM);
      wsum += wgt * l[s];
      o += wgt * Opart[(size_t)(dir * 4 + s) * S + (size_t)row * 64 + lane];
    }
    const float res = o / wsum;
    if (dir)
      A2[(size_t)row * 64 + lane] = res;
    else
      A1[(size_t)row * 64 + lane] = res;
  }
}

// ---------------- post: residual blocks + gate + head ----------------
__global__ __launch_bounds__(256) void post_kernel(
    const float* __restrict__ A1, const float* __restrict__ A2,
    const float* __restrict__ nirF, const float* __restrict__ libsF,
    const float* __restrict__ ln1g, const float* __restrict__ ln1b,
    const float* __restrict__ fc1w, const float* __restrict__ fc1b,
    const float* __restrict__ ln2g, const float* __restrict__ ln2b,
    const float* __restrict__ fc2w, const float* __restrict__ fc2b,
    const float* __restrict__ ln0g, const float* __restrict__ ln0b,
    const float* __restrict__ gatew, const float* __restrict__ gateb,
    const float* __restrict__ ln3g, const float* __restrict__ ln3b,
    const float* __restrict__ fc3w, const float* __restrict__ fc3b,
    const float* __restrict__ ln4g, const float* __restrict__ ln4b,
    const float* __restrict__ fc4w, const float* __restrict__ fc4b,
    float* __restrict__ out) {
  __shared__ float FC1[4096], FC2[4096], FC3[2048];
  __shared__ float rbuf[4][128];
  const int t = threadIdx.x, w = t >> 6, lane = t & 63;
  for (int i = t; i < 4096; i += 256) {
    FC1[i] = fc1w[i];
    FC2[i] = fc2w[i];
  }
  for (int i = t; i < 2048; i += 256) FC3[i] = fc3w[i];
  __syncthreads();
  for (int rr = 0; rr < 4; ++rr) {
    const int r = blockIdx.x * 16 + rr * 4 + w;
    const size_t ro = (size_t)r * 64;
    const float a1 = A1[ro + lane], a2 = A2[ro + lane];
    const float nv = nirF[ro + lane], lv = libsF[ro + lane];

    float s = wave_sum64(a2), ss = wave_sum64(a2 * a2);
    float mean = s * (1.f / 64);
    float rstd = rsqrtf(ss * (1.f / 64) - mean * mean + LN_EPS);
    rbuf[w][lane] = (a2 - mean) * rstd * ln1g[lane] + ln1b[lane];
    __syncthreads();
    float o1 = fc1b[lane];
#pragma unroll 8
    for (int i = 0; i < 64; ++i) o1 += rbuf[w][i] * FC1[i * 64 + lane];
    const float out1 = fmaxf(o1, 0.f) + lv;
    __syncthreads();

    s = wave_sum64(a1);
    ss = wave_sum64(a1 * a1);
    mean = s * (1.f / 64);
    rstd = rsqrtf(ss * (1.f / 64) - mean * mean + LN_EPS);
    rbuf[w][lane] = (a1 - mean) * rstd * ln2g[lane] + ln2b[lane];
    __syncthreads();
    float o2 = fc2b[lane];
#pragma unroll 8
    for (int i = 0; i < 64; ++i) o2 += rbuf[w][i] * FC2[i * 64 + lane];
    const float out2 = fmaxf(o2, 0.f) + nv;
    __syncthreads();

    s = wave_sum64(out1 + out2);
    ss = wave_sum64(out1 * out1 + out2 * out2);
    mean = s * (1.f / 128);
    rstd = rsqrtf(ss * (1.f / 128) - mean * mean + LN_EPS);
    rbuf[w][lane] = (out1 - mean) * rstd * ln0g[lane] + ln0b[lane];
    rbuf[w][64 + lane] =
        (out2 - mean) * rstd * ln0g[64 + lane] + ln0b[64 + lane];
    __syncthreads();
    float gg = gateb[lane];
#pragma unroll 8
    for (int i = 0; i < 128; ++i) gg += rbuf[w][i] * gatew[i * 64 + lane];
    gg = 1.f / (1.f + __expf(-gg));
    const float fused = gg * out1 + (1.f - gg) * out2;
    __syncthreads();

    s = wave_sum64(fused);
    ss = wave_sum64(fused * fused);
    mean = s * (1.f / 64);
    rstd = rsqrtf(ss * (1.f / 64) - mean * mean + LN_EPS);
    rbuf[w][lane] = (fused - mean) * rstd * ln3g[lane] + ln3b[lane];
    __syncthreads();
    if (lane < 32) {
      float h = fc3b[lane];
#pragma unroll 8
      for (int i = 0; i < 64; ++i) h += rbuf[w][i] * FC3[i * 32 + lane];
      h = fmaxf(h, 0.f);
      const float hs = grp32_sum(h), hss = grp32_sum(h * h);
      const float hm = hs * (1.f / 32);
      const float hr = rsqrtf(hss * (1.f / 32) - hm * hm + LN_EPS);
      const float y4 = (h - hm) * hr * ln4g[lane] + ln4b[lane];
      const float part = grp32_sum(y4 * fc4w[lane]);
      if (lane == 0) out[r] = part + fc4b[0];
    }
    __syncthreads();
  }
}

extern "C" void kernel_launch(void* const* d_in, const int* in_sizes, int n_in,
                              void* d_out, int out_size, void* d_ws,
                              size_t ws_size, hipStream_t stream) {
  const float* nir_data = (const float*)d_in[0];
  const float* libs_data = (const float*)d_in[1];
  const float* nir_ln_g = (const float*)d_in[2];
  const float* nir_ln_b = (const float*)d_in[3];
  const float* nir_w = (const float*)d_in[4];
  const float* nir_b = (const float*)d_in[5];
  const float* libs_ln_g = (const float*)d_in[6];
  const float* libs_ln_b = (const float*)d_in[7];
  const float* libs_w = (const float*)d_in[8];
  const float* libs_b = (const float*)d_in[9];
  const float* q_ln_w = (const float*)d_in[10];
  const float* q_ln_b = (const float*)d_in[11];
  const float* k_ln_w = (const float*)d_in[12];
  const float* k_ln_b = (const float*)d_in[13];
  const float* v_ln_w = (const float*)d_in[14];
  const float* v_ln_b = (const float*)d_in[15];
  const float* q_nl_w = (const float*)d_in[16];
  const float* q_nl_b = (const float*)d_in[17];
  const float* k_nl_w = (const float*)d_in[18];
  const float* k_nl_b = (const float*)d_in[19];
  const float* v_nl_w = (const float*)d_in[20];
  const float* v_nl_b = (const float*)d_in[21];
  const float* ln1_g = (const float*)d_in[22];
  const float* ln1_b = (const float*)d_in[23];
  const float* fc1_w = (const float*)d_in[24];
  const float* fc1_b = (const float*)d_in[25];
  const float* ln2_g = (const float*)d_in[26];
  const float* ln2_b = (const float*)d_in[27];
  const float* fc2_w = (const float*)d_in[28];
  const float* fc2_b = (const float*)d_in[29];
  const float* ln0_g = (const float*)d_in[30];
  const float* ln0_b = (const float*)d_in[31];
  const float* gate_w = (const float*)d_in[32];
  const float* gate_b = (const float*)d_in[33];
  const float* ln3_g = (const float*)d_in[34];
  const float* ln3_b = (const float*)d_in[35];
  const float* fc3_w = (const float*)d_in[36];
  const float* fc3_b = (const float*)d_in[37];
  const float* ln4_g = (const float*)d_in[38];
  const float* ln4_b = (const float*)d_in[39];
  const float* fc4_w = (const float*)d_in[40];
  const float* fc4_b = (const float*)d_in[41];

  const size_t S = (size_t)8192 * 64;
  u16* ub = (u16*)d_ws;
  u16* Qb_nir = ub + 0 * S;
  u16* Kb_nir = ub + 1 * S;
  u16* Vb_nir = ub + 2 * S;
  u16* Qb_libs = ub + 3 * S;
  u16* Kb_libs = ub + 4 * S;
  u16* Vb_libs = ub + 5 * S;
  float* fp = (float*)(ub + 6 * S);
  float* f_nir = fp + 0 * S;
  float* f_libs = fp + 1 * S;
  float* Opart = fp + 2 * S;            // 8 slabs
  float* A1 = fp + 10 * S;              // attn_libs_to_nir
  float* A2 = fp + 11 * S;              // attn_nir_to_libs
  float* mpart = fp + 12 * S;           // 8*8192
  float* lpart = mpart + 8 * 8192;

  // nir: Q uses q_nl, K/V use *_ln
  extract_kernel<215><<<512, 256, 0, stream>>>(
      nir_data, nir_ln_g, nir_ln_b, nir_w, nir_b, q_nl_w, q_nl_b, k_ln_w,
      k_ln_b, v_ln_w, v_ln_b, f_nir, Qb_nir, Kb_nir, Vb_nir);
  // libs: Q uses q_ln, K/V use *_nl
  extract_kernel<244><<<512, 256, 0, stream>>>(
      libs_data, libs_ln_g, libs_ln_b, libs_w, libs_b, q_ln_w, q_ln_b, k_nl_w,
      k_nl_b, v_nl_w, v_nl_b, f_libs, Qb_libs, Kb_libs, Vb_libs);

  // dir0: Q_libs x K_nir/V_nir -> A1 ; dir1: Q_nir x K_libs/V_libs -> A2
  attn_mfma_kernel<<<1024, 256, 0, stream>>>(Qb_libs, Kb_nir, Vb_nir, Qb_nir,
                                             Kb_libs, Vb_libs, Opart, mpart,
                                             lpart);

  merge_kernel<<<1024, 256, 0, stream>>>(Opart, mpart, lpart, A1, A2);

  post_kernel<<<512, 256, 0, stream>>>(
      A1, A2, f_nir, f_libs, ln1_g, ln1_b, fc1_w, fc1_b, ln2_g, ln2_b, fc2_w,
      fc2_b, ln0_g, ln0_b, gate_w, gate_b, ln3_g, ln3_b, fc3_w, fc3_b, ln4_g,
      ln4_b, fc4_w, fc4_b, (float*)d_out);
}

// Round 4
// 167.710 us; speedup vs baseline: 8.9527x; 1.4661x over previous
//
#include <hip/hip_runtime.h>
#include <hip/hip_bf16.h>
#include <math.h>

#define LN_EPS 1e-5f

typedef __attribute__((ext_vector_type(8))) short short8;
typedef __attribute__((ext_vector_type(4))) float f32x4;
typedef unsigned short u16;
typedef unsigned int u32;

__device__ __forceinline__ u16 f2bf(float f) {
  __hip_bfloat16 h = __float2bfloat16(f);
  return __builtin_bit_cast(u16, h);
}
__device__ __forceinline__ float bf2f(u16 u) {
  u32 x = ((u32)u) << 16;
  return __builtin_bit_cast(float, x);
}

// ---------------- wave reduction helpers ----------------
__device__ __forceinline__ float wave_sum64(float v) {
#pragma unroll
  for (int m = 1; m <= 32; m <<= 1) v += __shfl_xor(v, m, 64);
  return v;
}
__device__ __forceinline__ float grp32_sum(float v) {
#pragma unroll
  for (int m = 1; m <= 16; m <<= 1) v += __shfl_xor(v, m, 64);
  return v;
}

// ---------------- extractor + QKV projection (fused) ----------------
// QKV weights staged in LDS as bf16 (24KB); Wext read from global (L2-hot).
// Q output pre-scaled by 1/sqrt(64); Q/K/V emitted bf16 for MFMA attention.
template <int DM>
__global__ __launch_bounds__(256) void extract_kernel(
    const float* __restrict__ xin, const float* __restrict__ lng,
    const float* __restrict__ lnb, const float* __restrict__ Wext,
    const float* __restrict__ bext, const float* __restrict__ Wq,
    const float* __restrict__ bq, const float* __restrict__ Wk,
    const float* __restrict__ bk, const float* __restrict__ Wv,
    const float* __restrict__ bv, float* __restrict__ featOut,
    u16* __restrict__ Qout, u16* __restrict__ Kout, u16* __restrict__ Vout) {
  __shared__ u16 sWq[4096], sWk[4096], sWv[4096];
  __shared__ float ybuf[4][256];
  __shared__ float fbuf[4][64];
  const int t = threadIdx.x, w = t >> 6, lane = t & 63;
  for (int i = t; i < 4096; i += 256) {
    sWq[i] = f2bf(Wq[i]);
    sWk[i] = f2bf(Wk[i]);
    sWv[i] = f2bf(Wv[i]);
  }
  __syncthreads();
#pragma unroll
  for (int rr = 0; rr < 2; ++rr) {
    const int r = blockIdx.x * 8 + rr * 4 + w;
    const float* x = xin + (size_t)r * DM;
    float xr[4];
    float s = 0.f, ss = 0.f;
#pragma unroll
    for (int u = 0; u < 4; ++u) {
      const int idx = u * 64 + lane;
      const float v = (idx < DM) ? x[idx] : 0.f;
      xr[u] = v;
      s += v;
      ss += v * v;
    }
    s = wave_sum64(s);
    ss = wave_sum64(ss);
    const float mean = s / (float)DM;
    const float rstd = rsqrtf(ss / (float)DM - mean * mean + LN_EPS);
#pragma unroll
    for (int u = 0; u < 4; ++u) {
      const int idx = u * 64 + lane;
      if (idx < DM) ybuf[w][idx] = (xr[u] - mean) * rstd * lng[idx] + lnb[idx];
    }
    __syncthreads();
    float acc = bext[lane];
#pragma unroll 8
    for (int i = 0; i < DM; ++i) acc += ybuf[w][i] * Wext[i * 64 + lane];
    const float f = fmaxf(acc, 0.f);
    featOut[(size_t)r * 64 + lane] = f;
    fbuf[w][lane] = f;
    __syncthreads();
    float aq = bq[lane], ak = bk[lane], av = bv[lane];
#pragma unroll 8
    for (int i = 0; i < 64; ++i) {
      const float fv = fbuf[w][i];
      aq += fv * bf2f(sWq[i * 64 + lane]);
      ak += fv * bf2f(sWk[i * 64 + lane]);
      av += fv * bf2f(sWv[i * 64 + lane]);
    }
    Qout[(size_t)r * 64 + lane] = f2bf(aq * 0.125f);  // fold 1/sqrt(64)
    Kout[(size_t)r * 64 + lane] = f2bf(ak);
    Vout[(size_t)r * 64 + lane] = f2bf(av);
    __syncthreads();
  }
}

// ---------------- flash attention, bf16 MFMA, swapped-operand ----------------
// grid 1024: split = bid&7 (XCD-local 1024-row KV slice), dir = (bid>>3)&1,
// qt = bid>>4 (64 q-tiles of 128). Block = 4 waves x 32 q. KVBLK=64, 16 tiles.
// Swapped QK: sacc = mfma(kfrag, qa) -> lane holds P[q=l16][kv=16kb+4g+r]:
// no cross-lane softmax at all (no-max exp; l is a per-lane scalar, reduced
// once at the end). P repacked to B-fragments via per-wave pad-34 LDS buffer.
// K,V single-buffered (2 raw barriers/tile; global prefetch regs span them).
__global__ __launch_bounds__(256) void attn_mfma_kernel(
    const u16* __restrict__ Qb0, const u16* __restrict__ Kb0,
    const u16* __restrict__ Vb0, const u16* __restrict__ Qb1,
    const u16* __restrict__ Kb1, const u16* __restrict__ Vb1,
    float* __restrict__ Opart, float* __restrict__ lpart) {
  __shared__ __align__(16) u16 lds_k[4096];   // [kv][d] ^ ((kv&7)<<3)
  __shared__ __align__(16) u16 lds_vt[4096];  // [d][kv] ^ (((d>>1)&7)<<3)
  __shared__ __align__(16) u32 lds_p[4][1088];  // per-wave, rows q: stride 34

  const int bid = blockIdx.x;
  const int split = bid & 7;
  const int dir = (bid >> 3) & 1;
  const int qt = bid >> 4;
  const int slab = dir * 8 + split;
  const int kvbase = split * 1024;

  const u16* Q = dir ? Qb1 : Qb0;
  const u16* K = dir ? Kb1 : Kb0;
  const u16* V = dir ? Vb1 : Vb0;

  const int t = threadIdx.x;
  const int w = t >> 6;
  const int lane = t & 63;
  const int g = lane >> 4;
  const int l16 = lane & 15;
  const int qblk = qt * 128 + w * 32;

  // ---- Q B-fragments (2 q-subtiles x 2 k-chunks), pre-scaled at extract ----
  short8 qa[2][2];
#pragma unroll
  for (int sub = 0; sub < 2; ++sub)
#pragma unroll
    for (int c = 0; c < 2; ++c)
      qa[sub][c] = *reinterpret_cast<const short8*>(
          Q + (size_t)(qblk + sub * 16 + l16) * 64 + 32 * c + 8 * g);

  f32x4 oacc[2][4];
#pragma unroll
  for (int sub = 0; sub < 2; ++sub)
#pragma unroll
    for (int db = 0; db < 4; ++db) oacc[sub][db] = f32x4{0.f, 0.f, 0.f, 0.f};
  float l_run[2] = {0.f, 0.f};

  // ---- staging: thread owns kv rows kv0..+3, d cols d0..+3 ----
  const int kv0 = (t >> 4) << 2;
  const int d0 = (t & 15) << 2;
  ushort4 kh[4], vh[4];

#define LOADT(tile_)                                                          \
  {                                                                           \
    _Pragma("unroll") for (int j = 0; j < 4; ++j) {                           \
      const size_t off = ((size_t)(kvbase + (tile_)*64 + kv0 + j)) * 64 + d0; \
      kh[j] = *reinterpret_cast<const ushort4*>(K + off);                     \
      vh[j] = *reinterpret_cast<const ushort4*>(V + off);                     \
    }                                                                         \
  }

#define STORET()                                                              \
  {                                                                           \
    _Pragma("unroll") for (int j = 0; j < 4; ++j) {                           \
      const int row = kv0 + j;                                                \
      *reinterpret_cast<ushort4*>(                                            \
          &lds_k[(row * 64 + d0) ^ ((row & 7) << 3)]) = kh[j];                \
    }                                                                         \
    _Pragma("unroll") for (int i = 0; i < 4; ++i) {                           \
      const int row = d0 + i;                                                 \
      ushort4 vt;                                                             \
      vt.x = (&vh[0].x)[i];                                                   \
      vt.y = (&vh[1].x)[i];                                                   \
      vt.z = (&vh[2].x)[i];                                                   \
      vt.w = (&vh[3].x)[i];                                                   \
      *reinterpret_cast<ushort4*>(                                            \
          &lds_vt[(row * 64 + kv0) ^ (((row >> 1) & 7) << 3)]) = vt;          \
    }                                                                         \
  }

  LOADT(0);
  STORET();
  LOADT(1);
  asm volatile("s_waitcnt lgkmcnt(0)" ::: "memory");
  __builtin_amdgcn_s_barrier();
  asm volatile("" ::: "memory");

  for (int tile = 0; tile < 16; ++tile) {
    // ---- S^T = K Q : sacc[sub][kb] holds P[q=l16][kv=16kb+4g+r] ----
    f32x4 sacc[2][4];
#pragma unroll
    for (int sub = 0; sub < 2; ++sub)
#pragma unroll
      for (int kb = 0; kb < 4; ++kb) sacc[sub][kb] = f32x4{0.f, 0.f, 0.f, 0.f};
#pragma unroll
    for (int c = 0; c < 2; ++c) {
#pragma unroll
      for (int kb = 0; kb < 4; ++kb) {
        const int row = 16 * kb + l16;
        const int idx = (row * 64 + 32 * c + 8 * g) ^ ((l16 & 7) << 3);
        const short8 kfrag = *reinterpret_cast<const short8*>(&lds_k[idx]);
        sacc[0][kb] = __builtin_amdgcn_mfma_f32_16x16x32_bf16(
            kfrag, qa[0][c], sacc[0][kb], 0, 0, 0);
        sacc[1][kb] = __builtin_amdgcn_mfma_f32_16x16x32_bf16(
            kfrag, qa[1][c], sacc[1][kb], 0, 0, 0);
      }
    }

    // ---- no-max softmax: p = exp(s); pack to bf16 pairs; P-buffer write ----
#pragma unroll
    for (int sub = 0; sub < 2; ++sub) {
      float lsub = 0.f;
#pragma unroll
      for (int kb = 0; kb < 4; ++kb) {
        const float p0 = __expf(sacc[sub][kb][0]);
        const float p1 = __expf(sacc[sub][kb][1]);
        const float p2 = __expf(sacc[sub][kb][2]);
        const float p3 = __expf(sacc[sub][kb][3]);
        lsub += (p0 + p1) + (p2 + p3);
        u32 w0, w1;
        asm("v_cvt_pk_bf16_f32 %0, %1, %2" : "=v"(w0) : "v"(p0), "v"(p1));
        asm("v_cvt_pk_bf16_f32 %0, %1, %2" : "=v"(w1) : "v"(p2), "v"(p3));
        *reinterpret_cast<uint2*>(
            &lds_p[w][sub * 544 + l16 * 34 + 8 * kb + 2 * g]) =
            make_uint2(w0, w1);
      }
      l_run[sub] += lsub;
    }

    // ---- read P back as B-fragments (per-wave buffer, compiler-ordered) ----
    short8 pB[2][2];
#pragma unroll
    for (int sub = 0; sub < 2; ++sub)
#pragma unroll
      for (int c = 0; c < 2; ++c) {
        const int base = sub * 544 + l16 * 34 + 16 * c + 4 * g;
        const uint2 a = *reinterpret_cast<const uint2*>(&lds_p[w][base]);
        const uint2 b = *reinterpret_cast<const uint2*>(&lds_p[w][base + 2]);
        u32 q4[4] = {a.x, a.y, b.x, b.y};
        pB[sub][c] = __builtin_bit_cast(short8, *(ulonglong2*)q4);
      }

    // ---- O^T += V^T P^T : oacc[sub][db] = O[q=l16][d=16db+4g+r] ----
#pragma unroll
    for (int c = 0; c < 2; ++c) {
#pragma unroll
      for (int db = 0; db < 4; ++db) {
        const int row = 16 * db + l16;
        const int idx = (row * 64 + 32 * c + 8 * g) ^ (((row >> 1) & 7) << 3);
        const short8 vfrag = *reinterpret_cast<const short8*>(&lds_vt[idx]);
        oacc[0][db] = __builtin_amdgcn_mfma_f32_16x16x32_bf16(
            vfrag, pB[0][c], oacc[0][db], 0, 0, 0);
        oacc[1][db] = __builtin_amdgcn_mfma_f32_16x16x32_bf16(
            vfrag, pB[1][c], oacc[1][db], 0, 0, 0);
      }
    }

    // ---- rotate single K/V buffer: all reads done -> store next tile ----
    asm volatile("s_waitcnt lgkmcnt(0)" ::: "memory");
    __builtin_amdgcn_s_barrier();
    asm volatile("" ::: "memory");
    if (tile < 15) {
      STORET();
      if (tile < 14) LOADT(tile + 2);
    }
    asm volatile("s_waitcnt lgkmcnt(0)" ::: "memory");
    __builtin_amdgcn_s_barrier();
    asm volatile("" ::: "memory");
  }

  // ---- epilogue: unnormalized O + l ----
  const size_t S = (size_t)8192 * 64;
#pragma unroll
  for (int sub = 0; sub < 2; ++sub) {
    const int q = qblk + sub * 16 + l16;
#pragma unroll
    for (int db = 0; db < 4; ++db)
#pragma unroll
      for (int r = 0; r < 4; ++r)
        Opart[(size_t)slab * S + (size_t)q * 64 + 16 * db + 4 * g + r] =
            oacc[sub][db][r];
    float lv = l_run[sub];
    lv += __shfl_xor(lv, 16, 64);
    lv += __shfl_xor(lv, 32, 64);
    if (g == 0) lpart[slab * 8192 + q] = lv;
  }
#undef LOADT
#undef STORET
}

// ---------------- post: merge splits + residual blocks + gate + head ----------------
__global__ __launch_bounds__(256) void post_kernel(
    const float* __restrict__ Opart, const float* __restrict__ lpart,
    const float* __restrict__ nirF, const float* __restrict__ libsF,
    const float* __restrict__ ln1g, const float* __restrict__ ln1b,
    const float* __restrict__ fc1w, const float* __restrict__ fc1b,
    const float* __restrict__ ln2g, const float* __restrict__ ln2b,
    const float* __restrict__ fc2w, const float* __restrict__ fc2b,
    const float* __restrict__ ln0g, const float* __restrict__ ln0b,
    const float* __restrict__ gatew, const float* __restrict__ gateb,
    const float* __restrict__ ln3g, const float* __restrict__ ln3b,
    const float* __restrict__ fc3w, const float* __restrict__ fc3b,
    const float* __restrict__ ln4g, const float* __restrict__ ln4b,
    const float* __restrict__ fc4w, const float* __restrict__ fc4b,
    float* __restrict__ out) {
  __shared__ u16 FC1[4096], FC2[4096], FC3[2048];
  __shared__ u16 GW[8192];
  __shared__ float rbuf[4][128];
  const int t = threadIdx.x, w = t >> 6, lane = t & 63;
  const size_t S = (size_t)8192 * 64;
  for (int i = t; i < 4096; i += 256) {
    FC1[i] = f2bf(fc1w[i]);
    FC2[i] = f2bf(fc2w[i]);
  }
  for (int i = t; i < 2048; i += 256) FC3[i] = f2bf(fc3w[i]);
  for (int i = t; i < 8192; i += 256) GW[i] = f2bf(gatew[i]);
  __syncthreads();
#pragma unroll
  for (int rr = 0; rr < 2; ++rr) {
    const int r = blockIdx.x * 8 + rr * 4 + w;
    const size_t ro = (size_t)r * 64;

    // merge the 8 KV-splits per direction (no-max: plain sums)
    float a1 = 0.f, a2 = 0.f, l1 = 0.f, l2 = 0.f;
#pragma unroll
    for (int s = 0; s < 8; ++s) {
      a1 += Opart[(size_t)s * S + ro + lane];
      a2 += Opart[(size_t)(8 + s) * S + ro + lane];
      l1 += lpart[s * 8192 + r];
      l2 += lpart[(8 + s) * 8192 + r];
    }
    a1 /= l1;  // attn_libs_to_nir
    a2 /= l2;  // attn_nir_to_libs

    const float nv = nirF[ro + lane], lv_ = libsF[ro + lane];

    // out1 = relu(LN(a2; ln1) @ fc1 + b) + libs
    float s1 = wave_sum64(a2), ss1 = wave_sum64(a2 * a2);
    float mean = s1 * (1.f / 64);
    float rstd = rsqrtf(ss1 * (1.f / 64) - mean * mean + LN_EPS);
    rbuf[w][lane] = (a2 - mean) * rstd * ln1g[lane] + ln1b[lane];
    __syncthreads();
    float o1 = fc1b[lane];
#pragma unroll 8
    for (int i = 0; i < 64; ++i) o1 += rbuf[w][i] * bf2f(FC1[i * 64 + lane]);
    const float out1 = fmaxf(o1, 0.f) + lv_;
    __syncthreads();

    // out2 = relu(LN(a1; ln2) @ fc2 + b) + nir
    s1 = wave_sum64(a1);
    ss1 = wave_sum64(a1 * a1);
    mean = s1 * (1.f / 64);
    rstd = rsqrtf(ss1 * (1.f / 64) - mean * mean + LN_EPS);
    rbuf[w][lane] = (a1 - mean) * rstd * ln2g[lane] + ln2b[lane];
    __syncthreads();
    float o2 = fc2b[lane];
#pragma unroll 8
    for (int i = 0; i < 64; ++i) o2 += rbuf[w][i] * bf2f(FC2[i * 64 + lane]);
    const float out2 = fmaxf(o2, 0.f) + nv;
    __syncthreads();

    // gate
    s1 = wave_sum64(out1 + out2);
    ss1 = wave_sum64(out1 * out1 + out2 * out2);
    mean = s1 * (1.f / 128);
    rstd = rsqrtf(ss1 * (1.f / 128) - mean * mean + LN_EPS);
    rbuf[w][lane] = (out1 - mean) * rstd * ln0g[lane] + ln0b[lane];
    rbuf[w][64 + lane] =
        (out2 - mean) * rstd * ln0g[64 + lane] + ln0b[64 + lane];
    __syncthreads();
    float gg = gateb[lane];
#pragma unroll 8
    for (int i = 0; i < 128; ++i) gg += rbuf[w][i] * bf2f(GW[i * 64 + lane]);
    gg = 1.f / (1.f + __expf(-gg));
    const float fused = gg * out1 + (1.f - gg) * out2;
    __syncthreads();

    // head: LN -> fc3 -> relu -> LN -> fc4
    s1 = wave_sum64(fused);
    ss1 = wave_sum64(fused * fused);
    mean = s1 * (1.f / 64);
    rstd = rsqrtf(ss1 * (1.f / 64) - mean * mean + LN_EPS);
    rbuf[w][lane] = (fused - mean) * rstd * ln3g[lane] + ln3b[lane];
    __syncthreads();
    if (lane < 32) {
      float h = fc3b[lane];
#pragma unroll 8
      for (int i = 0; i < 64; ++i) h += rbuf[w][i] * bf2f(FC3[i * 32 + lane]);
      h = fmaxf(h, 0.f);
      const float hs = grp32_sum(h), hss = grp32_sum(h * h);
      const float hm = hs * (1.f / 32);
      const float hr = rsqrtf(hss * (1.f / 32) - hm * hm + LN_EPS);
      const float y4 = (h - hm) * hr * ln4g[lane] + ln4b[lane];
      const float part = grp32_sum(y4 * fc4w[lane]);
      if (lane == 0) out[r] = part + fc4b[0];
    }
    __syncthreads();
  }
}

extern "C" void kernel_launch(void* const* d_in, const int* in_sizes, int n_in,
                              void* d_out, int out_size, void* d_ws,
                              size_t ws_size, hipStream_t stream) {
  const float* nir_data = (const float*)d_in[0];
  const float* libs_data = (const float*)d_in[1];
  const float* nir_ln_g = (const float*)d_in[2];
  const float* nir_ln_b = (const float*)d_in[3];
  const float* nir_w = (const float*)d_in[4];
  const float* nir_b = (const float*)d_in[5];
  const float* libs_ln_g = (const float*)d_in[6];
  const float* libs_ln_b = (const float*)d_in[7];
  const float* libs_w = (const float*)d_in[8];
  const float* libs_b = (const float*)d_in[9];
  const float* q_ln_w = (const float*)d_in[10];
  const float* q_ln_b = (const float*)d_in[11];
  const float* k_ln_w = (const float*)d_in[12];
  const float* k_ln_b = (const float*)d_in[13];
  const float* v_ln_w = (const float*)d_in[14];
  const float* v_ln_b = (const float*)d_in[15];
  const float* q_nl_w = (const float*)d_in[16];
  const float* q_nl_b = (const float*)d_in[17];
  const float* k_nl_w = (const float*)d_in[18];
  const float* k_nl_b = (const float*)d_in[19];
  const float* v_nl_w = (const float*)d_in[20];
  const float* v_nl_b = (const float*)d_in[21];
  const float* ln1_g = (const float*)d_in[22];
  const float* ln1_b = (const float*)d_in[23];
  const float* fc1_w = (const float*)d_in[24];
  const float* fc1_b = (const float*)d_in[25];
  const float* ln2_g = (const float*)d_in[26];
  const float* ln2_b = (const float*)d_in[27];
  const float* fc2_w = (const float*)d_in[28];
  const float* fc2_b = (const float*)d_in[29];
  const float* ln0_g = (const float*)d_in[30];
  const float* ln0_b = (const float*)d_in[31];
  const float* gate_w = (const float*)d_in[32];
  const float* gate_b = (const float*)d_in[33];
  const float* ln3_g = (const float*)d_in[34];
  const float* ln3_b = (const float*)d_in[35];
  const float* fc3_w = (const float*)d_in[36];
  const float* fc3_b = (const float*)d_in[37];
  const float* ln4_g = (const float*)d_in[38];
  const float* ln4_b = (const float*)d_in[39];
  const float* fc4_w = (const float*)d_in[40];
  const float* fc4_b = (const float*)d_in[41];

  const size_t S = (size_t)8192 * 64;
  u16* ub = (u16*)d_ws;
  u16* Qb_nir = ub + 0 * S;
  u16* Kb_nir = ub + 1 * S;
  u16* Vb_nir = ub + 2 * S;
  u16* Qb_libs = ub + 3 * S;
  u16* Kb_libs = ub + 4 * S;
  u16* Vb_libs = ub + 5 * S;
  float* fp = (float*)(ub + 6 * S);
  float* f_nir = fp + 0 * S;
  float* f_libs = fp + 1 * S;
  float* Opart = fp + 2 * S;    // 16 slabs (2 dirs x 8 splits)
  float* lpart = fp + 18 * S;   // 16 x 8192

  // nir: Q uses q_nl, K/V use *_ln
  extract_kernel<215><<<1024, 256, 0, stream>>>(
      nir_data, nir_ln_g, nir_ln_b, nir_w, nir_b, q_nl_w, q_nl_b, k_ln_w,
      k_ln_b, v_ln_w, v_ln_b, f_nir, Qb_nir, Kb_nir, Vb_nir);
  // libs: Q uses q_ln, K/V use *_nl
  extract_kernel<244><<<1024, 256, 0, stream>>>(
      libs_data, libs_ln_g, libs_ln_b, libs_w, libs_b, q_ln_w, q_ln_b, k_nl_w,
      k_nl_b, v_nl_w, v_nl_b, f_libs, Qb_libs, Kb_libs, Vb_libs);

  // dir0: Q_libs x K/V_nir ; dir1: Q_nir x K/V_libs
  attn_mfma_kernel<<<1024, 256, 0, stream>>>(Qb_libs, Kb_nir, Vb_nir, Qb_nir,
                                             Kb_libs, Vb_libs, Opart, lpart);

  post_kernel<<<1024, 256, 0, stream>>>(
      Opart, lpart, f_nir, f_libs, ln1_g, ln1_b, fc1_w, fc1_b, ln2_g, ln2_b,
      fc2_w, fc2_b, ln0_g, ln0_b, gate_w, gate_b, ln3_g, ln3_b, fc3_w, fc3_b,
      ln4_g, ln4_b, fc4_w, fc4_b, (float*)d_out);
}

// Round 7
// 157.463 us; speedup vs baseline: 9.5353x; 1.0651x over previous
//
#include <hip/hip_runtime.h>
#include <hip/hip_bf16.h>
#include <math.h>

#define LN_EPS 1e-5f

typedef __attribute__((ext_vector_type(8))) short short8;
typedef __attribute__((ext_vector_type(4))) float f32x4;
typedef unsigned short u16;
typedef unsigned int u32;

__device__ __forceinline__ u16 f2bf(float f) {
  __hip_bfloat16 h = __float2bfloat16(f);
  return __builtin_bit_cast(u16, h);
}
__device__ __forceinline__ float bf2f(u16 u) {
  u32 x = ((u32)u) << 16;
  return __builtin_bit_cast(float, x);
}

// ---------------- wave reduction helpers ----------------
__device__ __forceinline__ float wave_sum64(float v) {
#pragma unroll
  for (int m = 1; m <= 32; m <<= 1) v += __shfl_xor(v, m, 64);
  return v;
}
__device__ __forceinline__ float grp32_sum(float v) {
#pragma unroll
  for (int m = 1; m <= 16; m <<= 1) v += __shfl_xor(v, m, 64);
  return v;
}

// ---------------- extractor + QKV projection (R4-proven, byte-identical) ----------------
template <int DM>
__global__ __launch_bounds__(256) void extract_kernel(
    const float* __restrict__ xin, const float* __restrict__ lng,
    const float* __restrict__ lnb, const float* __restrict__ Wext,
    const float* __restrict__ bext, const float* __restrict__ Wq,
    const float* __restrict__ bq, const float* __restrict__ Wk,
    const float* __restrict__ bk, const float* __restrict__ Wv,
    const float* __restrict__ bv, float* __restrict__ featOut,
    u16* __restrict__ Qout, u16* __restrict__ Kout, u16* __restrict__ Vout) {
  __shared__ u16 sWq[4096], sWk[4096], sWv[4096];
  __shared__ float ybuf[4][256];
  __shared__ float fbuf[4][64];
  const int t = threadIdx.x, w = t >> 6, lane = t & 63;
  for (int i = t; i < 4096; i += 256) {
    sWq[i] = f2bf(Wq[i]);
    sWk[i] = f2bf(Wk[i]);
    sWv[i] = f2bf(Wv[i]);
  }
  __syncthreads();
#pragma unroll
  for (int rr = 0; rr < 2; ++rr) {
    const int r = blockIdx.x * 8 + rr * 4 + w;
    const float* x = xin + (size_t)r * DM;
    float xr[4];
    float s = 0.f, ss = 0.f;
#pragma unroll
    for (int u = 0; u < 4; ++u) {
      const int idx = u * 64 + lane;
      const float v = (idx < DM) ? x[idx] : 0.f;
      xr[u] = v;
      s += v;
      ss += v * v;
    }
    s = wave_sum64(s);
    ss = wave_sum64(ss);
    const float mean = s / (float)DM;
    const float rstd = rsqrtf(ss / (float)DM - mean * mean + LN_EPS);
#pragma unroll
    for (int u = 0; u < 4; ++u) {
      const int idx = u * 64 + lane;
      if (idx < DM) ybuf[w][idx] = (xr[u] - mean) * rstd * lng[idx] + lnb[idx];
    }
    __syncthreads();
    float acc = bext[lane];
#pragma unroll 8
    for (int i = 0; i < DM; ++i) acc += ybuf[w][i] * Wext[i * 64 + lane];
    const float f = fmaxf(acc, 0.f);
    featOut[(size_t)r * 64 + lane] = f;
    fbuf[w][lane] = f;
    __syncthreads();
    float aq = bq[lane], ak = bk[lane], av = bv[lane];
#pragma unroll 8
    for (int i = 0; i < 64; ++i) {
      const float fv = fbuf[w][i];
      aq += fv * bf2f(sWq[i * 64 + lane]);
      ak += fv * bf2f(sWk[i * 64 + lane]);
      av += fv * bf2f(sWv[i * 64 + lane]);
    }
    Qout[(size_t)r * 64 + lane] = f2bf(aq * 0.125f);  // fold 1/sqrt(64)
    Kout[(size_t)r * 64 + lane] = f2bf(ak);
    Vout[(size_t)r * 64 + lane] = f2bf(av);
    __syncthreads();
  }
}

// ---------------- flash attention, bf16 MFMA, 64 q/wave ----------------
// Only delta vs the R4-proven kernel: 4 q-subtiles per wave (was 2), grid
// 512 (qt*256), lds_p widened, launch_bounds (256,2). __expf softmax and
// f32 Opart exactly as R4 (the R5/R6 inline-asm v_exp_f32 is banned: TRANS
// ops in opaque asm miss the compiler-inserted hazard s_nop).
__global__ __launch_bounds__(256, 2) void attn_mfma_kernel(
    const u16* __restrict__ Qb0, const u16* __restrict__ Kb0,
    const u16* __restrict__ Vb0, const u16* __restrict__ Qb1,
    const u16* __restrict__ Kb1, const u16* __restrict__ Vb1,
    float* __restrict__ Opart, float* __restrict__ lpart) {
  __shared__ __align__(16) u16 lds_k[4096];     // [kv][d] ^ ((kv&7)<<3)
  __shared__ __align__(16) u16 lds_vt[4096];    // [d][kv] ^ (((d>>1)&7)<<3)
  __shared__ __align__(16) u32 lds_p[4][2176];  // per-wave, [sub][16 q][34]

  const int bid = blockIdx.x;
  const int split = bid & 7;
  const int dir = (bid >> 3) & 1;
  const int qt = bid >> 4;
  const int slab = dir * 8 + split;
  const int kvbase = split * 1024;

  const u16* Q = dir ? Qb1 : Qb0;
  const u16* K = dir ? Kb1 : Kb0;
  const u16* V = dir ? Vb1 : Vb0;

  const int t = threadIdx.x;
  const int w = t >> 6;
  const int lane = t & 63;
  const int g = lane >> 4;
  const int l16 = lane & 15;
  const int qblk = qt * 256 + w * 64;

  // ---- Q B-fragments: 4 q-subtiles x 2 k-chunks (pre-scaled by 1/8) ----
  short8 qa[4][2];
#pragma unroll
  for (int sub = 0; sub < 4; ++sub)
#pragma unroll
    for (int c = 0; c < 2; ++c)
      qa[sub][c] = *reinterpret_cast<const short8*>(
          Q + (size_t)(qblk + sub * 16 + l16) * 64 + 32 * c + 8 * g);

  f32x4 oacc[4][4];
#pragma unroll
  for (int sub = 0; sub < 4; ++sub)
#pragma unroll
    for (int db = 0; db < 4; ++db) oacc[sub][db] = f32x4{0.f, 0.f, 0.f, 0.f};
  float l_run[4] = {0.f, 0.f, 0.f, 0.f};

  const int kv0 = (t >> 4) << 2;
  const int d0 = (t & 15) << 2;
  ushort4 kh[4], vh[4];

#define LOADT(tile_)                                                          \
  {                                                                           \
    _Pragma("unroll") for (int j = 0; j < 4; ++j) {                           \
      const size_t off = ((size_t)(kvbase + (tile_)*64 + kv0 + j)) * 64 + d0; \
      kh[j] = *reinterpret_cast<const ushort4*>(K + off);                     \
      vh[j] = *reinterpret_cast<const ushort4*>(V + off);                     \
    }                                                                         \
  }

#define STORET()                                                              \
  {                                                                           \
    _Pragma("unroll") for (int j = 0; j < 4; ++j) {                           \
      const int row = kv0 + j;                                                \
      *reinterpret_cast<ushort4*>(                                            \
          &lds_k[(row * 64 + d0) ^ ((row & 7) << 3)]) = kh[j];                \
    }                                                                         \
    _Pragma("unroll") for (int i = 0; i < 4; ++i) {                           \
      const int row = d0 + i;                                                 \
      ushort4 vt;                                                             \
      vt.x = (&vh[0].x)[i];                                                   \
      vt.y = (&vh[1].x)[i];                                                   \
      vt.z = (&vh[2].x)[i];                                                   \
      vt.w = (&vh[3].x)[i];                                                   \
      *reinterpret_cast<ushort4*>(                                            \
          &lds_vt[(row * 64 + kv0) ^ (((row >> 1) & 7) << 3)]) = vt;          \
    }                                                                         \
  }

  LOADT(0);
  STORET();
  LOADT(1);
  asm volatile("s_waitcnt lgkmcnt(0)" ::: "memory");
  __builtin_amdgcn_s_barrier();
  asm volatile("" ::: "memory");

  for (int tile = 0; tile < 16; ++tile) {
    // ---- S^T = K Q for all 4 subs (K-fragment loaded once) ----
    f32x4 sacc[4][4];
#pragma unroll
    for (int sub = 0; sub < 4; ++sub)
#pragma unroll
      for (int kb = 0; kb < 4; ++kb) sacc[sub][kb] = f32x4{0.f, 0.f, 0.f, 0.f};
#pragma unroll
    for (int c = 0; c < 2; ++c) {
#pragma unroll
      for (int kb = 0; kb < 4; ++kb) {
        const int row = 16 * kb + l16;
        const int idx = (row * 64 + 32 * c + 8 * g) ^ ((row & 7) << 3);
        const short8 kfrag = *reinterpret_cast<const short8*>(&lds_k[idx]);
#pragma unroll
        for (int sub = 0; sub < 4; ++sub)
          sacc[sub][kb] = __builtin_amdgcn_mfma_f32_16x16x32_bf16(
              kfrag, qa[sub][c], sacc[sub][kb], 0, 0, 0);
      }
    }

    // ---- no-max softmax (__expf); pack bf16; P round-trip via LDS ----
    short8 pB[4][2];
#pragma unroll
    for (int sub = 0; sub < 4; ++sub) {
      float lsub = 0.f;
#pragma unroll
      for (int kb = 0; kb < 4; ++kb) {
        const float p0 = __expf(sacc[sub][kb][0]);
        const float p1 = __expf(sacc[sub][kb][1]);
        const float p2 = __expf(sacc[sub][kb][2]);
        const float p3 = __expf(sacc[sub][kb][3]);
        lsub += (p0 + p1) + (p2 + p3);
        u32 w0, w1;
        asm("v_cvt_pk_bf16_f32 %0, %1, %2" : "=v"(w0) : "v"(p0), "v"(p1));
        asm("v_cvt_pk_bf16_f32 %0, %1, %2" : "=v"(w1) : "v"(p2), "v"(p3));
        *reinterpret_cast<uint2*>(
            &lds_p[w][sub * 544 + l16 * 34 + 8 * kb + 2 * g]) =
            make_uint2(w0, w1);
      }
      l_run[sub] += lsub;
#pragma unroll
      for (int c = 0; c < 2; ++c) {
        const int base = sub * 544 + l16 * 34 + 16 * c + 4 * g;
        const uint2 a = *reinterpret_cast<const uint2*>(&lds_p[w][base]);
        const uint2 bb = *reinterpret_cast<const uint2*>(&lds_p[w][base + 2]);
        u32 q4[4] = {a.x, a.y, bb.x, bb.y};
        pB[sub][c] = __builtin_bit_cast(short8, *(ulonglong2*)q4);
      }
    }

    // ---- O^T += V^T P^T (V-fragment loaded once, shared by 4 subs) ----
#pragma unroll
    for (int c = 0; c < 2; ++c) {
#pragma unroll
      for (int db = 0; db < 4; ++db) {
        const int row = 16 * db + l16;
        const int idx = (row * 64 + 32 * c + 8 * g) ^ (((row >> 1) & 7) << 3);
        const short8 vfrag = *reinterpret_cast<const short8*>(&lds_vt[idx]);
#pragma unroll
        for (int sub = 0; sub < 4; ++sub)
          oacc[sub][db] = __builtin_amdgcn_mfma_f32_16x16x32_bf16(
              vfrag, pB[sub][c], oacc[sub][db], 0, 0, 0);
      }
    }

    // ---- rotate single K/V buffer ----
    asm volatile("s_waitcnt lgkmcnt(0)" ::: "memory");
    __builtin_amdgcn_s_barrier();
    asm volatile("" ::: "memory");
    if (tile < 15) {
      STORET();
      if (tile < 14) LOADT(tile + 2);
    }
    asm volatile("s_waitcnt lgkmcnt(0)" ::: "memory");
    __builtin_amdgcn_s_barrier();
    asm volatile("" ::: "memory");
  }

  // ---- epilogue: f32 unnormalized O + f32 l (R4-proven format) ----
  const size_t S = (size_t)8192 * 64;
#pragma unroll
  for (int sub = 0; sub < 4; ++sub) {
    const int q = qblk + sub * 16 + l16;
#pragma unroll
    for (int db = 0; db < 4; ++db)
#pragma unroll
      for (int r = 0; r < 4; ++r)
        Opart[(size_t)slab * S + (size_t)q * 64 + 16 * db + 4 * g + r] =
            oacc[sub][db][r];
    float lv = l_run[sub];
    lv += __shfl_xor(lv, 16, 64);
    lv += __shfl_xor(lv, 32, 64);
    if (g == 0) lpart[slab * 8192 + q] = lv;
  }
#undef LOADT
#undef STORET
}

// ---------------- post (R4-proven, byte-identical) ----------------
__global__ __launch_bounds__(256) void post_kernel(
    const float* __restrict__ Opart, const float* __restrict__ lpart,
    const float* __restrict__ nirF, const float* __restrict__ libsF,
    const float* __restrict__ ln1g, const float* __restrict__ ln1b,
    const float* __restrict__ fc1w, const float* __restrict__ fc1b,
    const float* __restrict__ ln2g, const float* __restrict__ ln2b,
    const float* __restrict__ fc2w, const float* __restrict__ fc2b,
    const float* __restrict__ ln0g, const float* __restrict__ ln0b,
    const float* __restrict__ gatew, const float* __restrict__ gateb,
    const float* __restrict__ ln3g, const float* __restrict__ ln3b,
    const float* __restrict__ fc3w, const float* __restrict__ fc3b,
    const float* __restrict__ ln4g, const float* __restrict__ ln4b,
    const float* __restrict__ fc4w, const float* __restrict__ fc4b,
    float* __restrict__ out) {
  __shared__ u16 FC1[4096], FC2[4096], FC3[2048];
  __shared__ u16 GW[8192];
  __shared__ float rbuf[4][128];
  const int t = threadIdx.x, w = t >> 6, lane = t & 63;
  const size_t S = (size_t)8192 * 64;
  for (int i = t; i < 4096; i += 256) {
    FC1[i] = f2bf(fc1w[i]);
    FC2[i] = f2bf(fc2w[i]);
  }
  for (int i = t; i < 2048; i += 256) FC3[i] = f2bf(fc3w[i]);
  for (int i = t; i < 8192; i += 256) GW[i] = f2bf(gatew[i]);
  __syncthreads();
#pragma unroll
  for (int rr = 0; rr < 2; ++rr) {
    const int r = blockIdx.x * 8 + rr * 4 + w;
    const size_t ro = (size_t)r * 64;

    // merge 8 KV-splits per direction (no-max: plain sums)
    float a1 = 0.f, a2 = 0.f, l1 = 0.f, l2 = 0.f;
#pragma unroll
    for (int s = 0; s < 8; ++s) {
      a1 += Opart[(size_t)s * S + ro + lane];
      a2 += Opart[(size_t)(8 + s) * S + ro + lane];
      l1 += lpart[s * 8192 + r];
      l2 += lpart[(8 + s) * 8192 + r];
    }
    a1 /= l1;  // attn_libs_to_nir
    a2 /= l2;  // attn_nir_to_libs

    const float nv = nirF[ro + lane], lv_ = libsF[ro + lane];

    // out1 = relu(LN(a2; ln1) @ fc1 + b) + libs
    float s1 = wave_sum64(a2), ss1 = wave_sum64(a2 * a2);
    float mean = s1 * (1.f / 64);
    float rstd = rsqrtf(ss1 * (1.f / 64) - mean * mean + LN_EPS);
    rbuf[w][lane] = (a2 - mean) * rstd * ln1g[lane] + ln1b[lane];
    __syncthreads();
    float o1 = fc1b[lane];
#pragma unroll 8
    for (int i = 0; i < 64; ++i)
      o1 = fmaf(rbuf[w][i], bf2f(FC1[i * 64 + lane]), o1);
    const float out1 = fmaxf(o1, 0.f) + lv_;
    __syncthreads();

    // out2 = relu(LN(a1; ln2) @ fc2 + b) + nir
    s1 = wave_sum64(a1);
    ss1 = wave_sum64(a1 * a1);
    mean = s1 * (1.f / 64);
    rstd = rsqrtf(ss1 * (1.f / 64) - mean * mean + LN_EPS);
    rbuf[w][lane] = (a1 - mean) * rstd * ln2g[lane] + ln2b[lane];
    __syncthreads();
    float o2 = fc2b[lane];
#pragma unroll 8
    for (int i = 0; i < 64; ++i)
      o2 = fmaf(rbuf[w][i], bf2f(FC2[i * 64 + lane]), o2);
    const float out2 = fmaxf(o2, 0.f) + nv;
    __syncthreads();

    // gate
    s1 = wave_sum64(out1 + out2);
    ss1 = wave_sum64(out1 * out1 + out2 * out2);
    mean = s1 * (1.f / 128);
    rstd = rsqrtf(ss1 * (1.f / 128) - mean * mean + LN_EPS);
    rbuf[w][lane] = (out1 - mean) * rstd * ln0g[lane] + ln0b[lane];
    rbuf[w][64 + lane] =
        (out2 - mean) * rstd * ln0g[64 + lane] + ln0b[64 + lane];
    __syncthreads();
    float gg = gateb[lane];
#pragma unroll 8
    for (int i = 0; i < 128; ++i)
      gg = fmaf(rbuf[w][i], bf2f(GW[i * 64 + lane]), gg);
    gg = 1.f / (1.f + __expf(-gg));
    const float fused = gg * out1 + (1.f - gg) * out2;
    __syncthreads();

    // head: LN -> fc3 -> relu -> LN -> fc4
    s1 = wave_sum64(fused);
    ss1 = wave_sum64(fused * fused);
    mean = s1 * (1.f / 64);
    rstd = rsqrtf(ss1 * (1.f / 64) - mean * mean + LN_EPS);
    rbuf[w][lane] = (fused - mean) * rstd * ln3g[lane] + ln3b[lane];
    __syncthreads();
    if (lane < 32) {
      float h = fc3b[lane];
#pragma unroll 8
      for (int i = 0; i < 64; ++i)
        h = fmaf(rbuf[w][i], bf2f(FC3[i * 32 + lane]), h);
      h = fmaxf(h, 0.f);
      const float hs = grp32_sum(h), hss = grp32_sum(h * h);
      const float hm = hs * (1.f / 32);
      const float hr = rsqrtf(hss * (1.f / 32) - hm * hm + LN_EPS);
      const float y4 = (h - hm) * hr * ln4g[lane] + ln4b[lane];
      const float part = grp32_sum(y4 * fc4w[lane]);
      if (lane == 0) out[r] = part + fc4b[0];
    }
    __syncthreads();
  }
}

extern "C" void kernel_launch(void* const* d_in, const int* in_sizes, int n_in,
                              void* d_out, int out_size, void* d_ws,
                              size_t ws_size, hipStream_t stream) {
  const float* nir_data = (const float*)d_in[0];
  const float* libs_data = (const float*)d_in[1];
  const float* nir_ln_g = (const float*)d_in[2];
  const float* nir_ln_b = (const float*)d_in[3];
  const float* nir_w = (const float*)d_in[4];
  const float* nir_b = (const float*)d_in[5];
  const float* libs_ln_g = (const float*)d_in[6];
  const float* libs_ln_b = (const float*)d_in[7];
  const float* libs_w = (const float*)d_in[8];
  const float* libs_b = (const float*)d_in[9];
  const float* q_ln_w = (const float*)d_in[10];
  const float* q_ln_b = (const float*)d_in[11];
  const float* k_ln_w = (const float*)d_in[12];
  const float* k_ln_b = (const float*)d_in[13];
  const float* v_ln_w = (const float*)d_in[14];
  const float* v_ln_b = (const float*)d_in[15];
  const float* q_nl_w = (const float*)d_in[16];
  const float* q_nl_b = (const float*)d_in[17];
  const float* k_nl_w = (const float*)d_in[18];
  const float* k_nl_b = (const float*)d_in[19];
  const float* v_nl_w = (const float*)d_in[20];
  const float* v_nl_b = (const float*)d_in[21];
  const float* ln1_g = (const float*)d_in[22];
  const float* ln1_b = (const float*)d_in[23];
  const float* fc1_w = (const float*)d_in[24];
  const float* fc1_b = (const float*)d_in[25];
  const float* ln2_g = (const float*)d_in[26];
  const float* ln2_b = (const float*)d_in[27];
  const float* fc2_w = (const float*)d_in[28];
  const float* fc2_b = (const float*)d_in[29];
  const float* ln0_g = (const float*)d_in[30];
  const float* ln0_b = (const float*)d_in[31];
  const float* gate_w = (const float*)d_in[32];
  const float* gate_b = (const float*)d_in[33];
  const float* ln3_g = (const float*)d_in[34];
  const float* ln3_b = (const float*)d_in[35];
  const float* fc3_w = (const float*)d_in[36];
  const float* fc3_b = (const float*)d_in[37];
  const float* ln4_g = (const float*)d_in[38];
  const float* ln4_b = (const float*)d_in[39];
  const float* fc4_w = (const float*)d_in[40];
  const float* fc4_b = (const float*)d_in[41];

  const size_t S = (size_t)8192 * 64;
  u16* ub = (u16*)d_ws;
  u16* Qb_nir = ub + 0 * S;
  u16* Kb_nir = ub + 1 * S;
  u16* Vb_nir = ub + 2 * S;
  u16* Qb_libs = ub + 3 * S;
  u16* Kb_libs = ub + 4 * S;
  u16* Vb_libs = ub + 5 * S;
  float* fp = (float*)(ub + 6 * S);
  float* f_nir = fp + 0 * S;
  float* f_libs = fp + 1 * S;
  float* Opart = fp + 2 * S;   // 16 f32 slabs (2 dirs x 8 splits)
  float* lpart = fp + 18 * S;  // 16 x 8192

  // nir: Q uses q_nl, K/V use *_ln
  extract_kernel<215><<<1024, 256, 0, stream>>>(
      nir_data, nir_ln_g, nir_ln_b, nir_w, nir_b, q_nl_w, q_nl_b, k_ln_w,
      k_ln_b, v_ln_w, v_ln_b, f_nir, Qb_nir, Kb_nir, Vb_nir);
  // libs: Q uses q_ln, K/V use *_nl
  extract_kernel<244><<<1024, 256, 0, stream>>>(
      libs_data, libs_ln_g, libs_ln_b, libs_w, libs_b, q_ln_w, q_ln_b, k_nl_w,
      k_nl_b, v_nl_w, v_nl_b, f_libs, Qb_libs, Kb_libs, Vb_libs);

  // dir0: Q_libs x K/V_nir ; dir1: Q_nir x K/V_libs
  attn_mfma_kernel<<<512, 256, 0, stream>>>(Qb_libs, Kb_nir, Vb_nir, Qb_nir,
                                            Kb_libs, Vb_libs, Opart, lpart);

  post_kernel<<<1024, 256, 0, stream>>>(
      Opart, lpart, f_nir, f_libs, ln1_g, ln1_b, fc1_w, fc1_b, ln2_g, ln2_b,
      fc2_w, fc2_b, ln0_g, ln0_b, gate_w, gate_b, ln3_g, ln3_b, fc3_w, fc3_b,
      ln4_g, ln4_b, fc4_w, fc4_b, (float*)d_out);
}